// Round 14
// baseline (1397.094 us; speedup 1.0000x reference)
//
#include <hip/hip_runtime.h>
#include <math.h>

#define NTOK   131040   // 8*91*180
#define NTOKW  138240   // 15*64*144

typedef __attribute__((ext_vector_type(8))) short bf16x8;
typedef __attribute__((ext_vector_type(8))) unsigned short u16x8;
typedef __attribute__((ext_vector_type(4))) float f32x4;
typedef __attribute__((ext_vector_type(2))) float f32x2;

__device__ __forceinline__ float b2f(unsigned short u){
  union { unsigned u; float f; } v; v.u = ((unsigned)u) << 16; return v.f;
}
__device__ __forceinline__ unsigned short f2b(float f){
  union { float f; unsigned u; } v; v.f = f;
  unsigned r = v.u + 0x7FFFu + ((v.u >> 16) & 1u);
  return (unsigned short)(r >> 16);
}
// tanh-GELU via rcpf (no f32 div sequence); |err vs erf-GELU| ~3e-4
__device__ __forceinline__ float gelu_fast(float x){
  float t = 0.79788456080286536f * (x + 0.044715f * x * x * x);
  float e = __expf(2.0f * t);
  float th = 1.0f - 2.0f * __builtin_amdgcn_rcpf(e + 1.0f);
  return 0.5f * x * (1.0f + th);
}
__device__ __forceinline__ unsigned pk_bf16(float lo, float hi){
  unsigned r;
  asm("v_cvt_pk_bf16_f32 %0, %1, %2" : "=v"(r) : "v"(lo), "v"(hi));
  return r;
}
__device__ __forceinline__ void lds_barrier(){
  asm volatile("s_waitcnt lgkmcnt(0)" ::: "memory");
  __builtin_amdgcn_sched_barrier(0);
  __builtin_amdgcn_s_barrier();
  __builtin_amdgcn_sched_barrier(0);
}

// transpose-cast: dst[n][k] = (bf16)src[k][n]
__global__ __launch_bounds__(256) void transp(const float* __restrict__ src,
                                              unsigned short* __restrict__ dst,
                                              int K, int N){
  int i = blockIdx.x*256 + threadIdx.x;
  if (i < K*N){
    int n = i / K, k = i % K;
    dst[i] = f2b(src[(size_t)k*N + n]);
  }
}

// precompute bias+mask in MFMA-fragment layout:
// bw[(((slice*9 + wv)*5 + vec)*64 + lane)*8 + elem], e = vec*8+elem = ct*4+r (<36)
__global__ __launch_bounds__(256) void bias_pre(
    const float* __restrict__ btab,
    unsigned short* __restrict__ bw,
    int roll)
{
  int gid = blockIdx.x*256 + threadIdx.x;   // < 384*9*64*40
  int e    = gid % 40;
  int rem  = gid / 40;
  int lane = rem % 64;
  int rem2 = rem / 64;
  int wv   = rem2 % 9;
  int slice= rem2 / 9;
  unsigned short out = 0;
  if (e < 36){
    int ct = e >> 2, r = e & 3;
    int i = wv*16 + (lane>>4)*4 + r;
    int j = ct*16 + (lane & 15);
    int tw = slice / 6, head = slice % 6;
    int ia = i/72, ib = (i%72)/12, ic = i%12;
    int ja = j/72, jb = (j%72)/12, jc = j%12;
    int idx = (ia + 2*ja)*828 + (ib + 6*jb)*23 + (ic - jc + 11);
    float v = btab[(size_t)idx*384 + tw*6 + head];
    if (roll){
      int nz = tw >> 4, nh = tw & 15;
      int zi = nz*2+ia, hi = nh*6+ib, zj = nz*2+ja, hj = nh*6+jb;
      int ri = 3*((zi<6)?0:((zi<7)?1:2)) + ((hi<90)?0:((hi<93)?1:2));
      int rj = 3*((zj<6)?0:((zj<7)?1:2)) + ((hj<90)?0:((hj<93)?1:2));
      if (ri != rj) v -= 100.0f;
    }
    out = f2b(v);
  }
  int vec = e >> 3, elem = e & 7;
  size_t di = ((((size_t)slice*9 + wv)*5 + vec)*64 + lane)*8 + elem;
  bw[di] = out;
}

// window-partition gather (+pad +roll), fp32 -> bf16
__global__ __launch_bounds__(256) void gather_win(const float* __restrict__ x,
                                                  unsigned short* __restrict__ xw,
                                                  int roll){
  int gid = blockIdx.x*256 + threadIdx.x;
  int row = gid / 24;
  int dp  = gid % 24;
  int tok = row % 144;
  int wt  = row / 144;
  int tw  = wt & 63;
  int w   = wt >> 6;
  int nz = tw >> 4, nh = tw & 15;
  int wz = tok / 72; int rem = tok % 72; int wh = rem / 12; int ww = rem % 12;
  int z = nz*2 + wz, h = nh*6 + wh, wc = w*12 + ww;
  if (roll){ z = (z+1)&7; h = (h+3)%96; wc = (wc+6)%180; }
  int d0 = dp*8;
  u16x8 o;
  if (h < 91){
    const float* s = x + ((size_t)((z*91 + h)*180 + wc))*192 + d0;
    #pragma unroll
    for (int i=0;i<8;i++) o[i] = f2b(s[i]);
  } else {
    #pragma unroll
    for (int i=0;i<8;i++) o[i] = 0;
  }
  *(u16x8*)(xw + (size_t)row*192 + d0) = o;
}

// K=192 GEMM: C[M x N] = A[M x 192] @ Bt[N x 192]^T + bias
__global__ __launch_bounds__(512) void gemm_k192(
    const unsigned short* __restrict__ A,
    const unsigned short* __restrict__ Bt,
    const float* __restrict__ bias,
    unsigned short* __restrict__ C,
    int N)
{
  __shared__ unsigned short Bst[192][200];
  int m0 = blockIdx.x * 128;
  int n0 = blockIdx.y * 192;
  int t = threadIdx.x;
  int lane = t & 63, w = t >> 6;
  int wm = w >> 2, wn = w & 3;
  int lg = lane >> 4, lr = lane & 15;

  #pragma unroll
  for (int i=0;i<9;i++){
    int idx = t + i*512;
    int r = idx / 24, c = (idx % 24)*8;
    *(u16x8*)&Bst[r][c] = *(const u16x8*)(Bt + (size_t)(n0 + r)*192 + c);
  }
  __syncthreads();

  const unsigned short* aRow = A + (size_t)(m0 + wm*64 + lr)*192 + lg*8;

  f32x4 acc[4][3];
  #pragma unroll
  for (int a=0;a<4;a++)
    #pragma unroll
    for (int b=0;b<3;b++) acc[a][b] = (f32x4){0.f,0.f,0.f,0.f};

  bf16x8 aP[2][6];
  #pragma unroll
  for (int ks=0; ks<6; ks++) aP[0][ks] = *(const bf16x8*)(aRow + ks*32);

  #pragma unroll
  for (int rt=0; rt<4; rt++){
    if (rt < 3){
      const unsigned short* an = aRow + (size_t)(rt+1)*16*192;
      #pragma unroll
      for (int ks=0; ks<6; ks++) aP[(rt+1)&1][ks] = *(const bf16x8*)(an + ks*32);
    }
    #pragma unroll
    for (int ks=0; ks<6; ks++){
      bf16x8 b0 = *(const bf16x8*)&Bst[wn*48 +      lr][ks*32 + lg*8];
      bf16x8 b1 = *(const bf16x8*)&Bst[wn*48 + 16 + lr][ks*32 + lg*8];
      bf16x8 b2 = *(const bf16x8*)&Bst[wn*48 + 32 + lr][ks*32 + lg*8];
      bf16x8 af = aP[rt&1][ks];
      acc[rt][0] = __builtin_amdgcn_mfma_f32_16x16x32_bf16(af, b0, acc[rt][0], 0,0,0);
      acc[rt][1] = __builtin_amdgcn_mfma_f32_16x16x32_bf16(af, b1, acc[rt][1], 0,0,0);
      acc[rt][2] = __builtin_amdgcn_mfma_f32_16x16x32_bf16(af, b2, acc[rt][2], 0,0,0);
    }
  }

  #pragma unroll
  for (int rt=0; rt<4; rt++){
    #pragma unroll
    for (int fn=0; fn<3; fn++){
      int colg = n0 + wn*48 + fn*16 + lr;
      float bv = bias[colg];
      #pragma unroll
      for (int r=0;r<4;r++){
        int rowg = m0 + wm*64 + rt*16 + lg*4 + r;
        C[(size_t)rowg*N + colg] = f2b(acc[rt][fn][r] + bv);
      }
    }
  }
}

// fused windowed attention: one block per (window-pair, head). 9 waves.
// bias via fragment-layout table: 5 coalesced u16x8 loads per lane.
__global__ __launch_bounds__(576) void attn_win(
    const unsigned short* __restrict__ qkv,
    const unsigned short* __restrict__ bw,
    unsigned short* __restrict__ outp)
{
  __shared__ union {
    struct { unsigned short Qs[144][32]; unsigned short Ks[144][40]; } qk;
    unsigned short Ps[144][160];
  } U;
  __shared__ unsigned short Vst[32][160];

  int b = blockIdx.x;
  int head = b % 6;
  int wt = b / 6;
  int tw = wt & 63;
  int t = threadIdx.x;
  int lane = t & 63;
  int wv = t >> 6;
  int lg = lane >> 4, lr = lane & 15;

  {
    int tok = t >> 2, c0 = (t & 3)*8;
    size_t base = ((size_t)wt*144 + tok)*576 + head*32 + c0;
    u16x8 qv = *(const u16x8*)(qkv + base);
    u16x8 kv = *(const u16x8*)(qkv + base + 192);
    u16x8 vv = *(const u16x8*)(qkv + base + 384);
    u16x8 qs;
    #pragma unroll
    for (int i=0;i<8;i++) qs[i] = f2b(b2f(qv[i]) * 0.17677669529663687f);
    *(u16x8*)&U.qk.Qs[tok][c0] = qs;
    *(u16x8*)&U.qk.Ks[tok][c0] = kv;
    #pragma unroll
    for (int i=0;i<8;i++) Vst[c0+i][tok] = vv[i];
  }
  if (t < 512) Vst[t >> 4][144 + (t & 15)] = 0;

  u16x8 bv0, bv1, bv2, bv3, bv4;
  {
    size_t sbase = ((((size_t)(tw*6 + head))*9 + wv)*5*64 + lane)*8;
    bv0 = *(const u16x8*)(bw + sbase);
    bv1 = *(const u16x8*)(bw + sbase + 64*8);
    bv2 = *(const u16x8*)(bw + sbase + 2*64*8);
    bv3 = *(const u16x8*)(bw + sbase + 3*64*8);
    bv4 = *(const u16x8*)(bw + sbase + 4*64*8);
  }
  __syncthreads();

  float s[9][4];
  {
    bf16x8 a = *(const bf16x8*)&U.qk.Qs[wv*16 + lr][lg*8];
    #pragma unroll
    for (int ct=0; ct<9; ct++){
      bf16x8 bb = *(const bf16x8*)&U.qk.Ks[ct*16 + lr][lg*8];
      f32x4 d = {0.f,0.f,0.f,0.f};
      d = __builtin_amdgcn_mfma_f32_16x16x32_bf16(a, bb, d, 0,0,0);
      s[ct][0]=d[0]; s[ct][1]=d[1]; s[ct][2]=d[2]; s[ct][3]=d[3];
    }
  }

  #pragma unroll
  for (int ct=0; ct<9; ct++){
    #pragma unroll
    for (int r=0;r<4;r++){
      const int e = ct*4 + r;
      unsigned short bu =
        (e < 8)  ? bv0[e & 7] :
        (e < 16) ? bv1[e & 7] :
        (e < 24) ? bv2[e & 7] :
        (e < 32) ? bv3[e & 7] : bv4[e & 7];
      s[ct][r] += b2f(bu);
    }
  }

  float mx[4] = {-1e30f,-1e30f,-1e30f,-1e30f};
  #pragma unroll
  for (int ct=0; ct<9; ct++)
    #pragma unroll
    for (int r=0;r<4;r++) mx[r] = fmaxf(mx[r], s[ct][r]);
  #pragma unroll
  for (int off=1; off<16; off<<=1)
    #pragma unroll
    for (int r=0;r<4;r++) mx[r] = fmaxf(mx[r], __shfl_xor(mx[r], off));
  float sm[4] = {0.f,0.f,0.f,0.f};
  #pragma unroll
  for (int ct=0; ct<9; ct++)
    #pragma unroll
    for (int r=0;r<4;r++){ s[ct][r] = __expf(s[ct][r] - mx[r]); sm[r] += s[ct][r]; }
  #pragma unroll
  for (int off=1; off<16; off<<=1)
    #pragma unroll
    for (int r=0;r<4;r++) sm[r] += __shfl_xor(sm[r], off);
  float inv[4];
  #pragma unroll
  for (int r=0;r<4;r++) inv[r] = 1.0f / sm[r];

  lds_barrier();

  #pragma unroll
  for (int ct=0; ct<9; ct++)
    #pragma unroll
    for (int r=0;r<4;r++)
      U.Ps[wv*16 + lg*4 + r][ct*16 + lr] = f2b(s[ct][r] * inv[r]);
  #pragma unroll
  for (int r=0;r<4;r++) U.Ps[wv*16 + lg*4 + r][144 + lr] = 0;
  __syncthreads();

  #pragma unroll
  for (int ct2=0; ct2<2; ct2++){
    f32x4 o = {0.f,0.f,0.f,0.f};
    #pragma unroll
    for (int kt=0; kt<5; kt++){
      bf16x8 a  = *(const bf16x8*)&U.Ps[wv*16 + lr][kt*32 + lg*8];
      bf16x8 bb = *(const bf16x8*)&Vst[ct2*16 + lr][kt*32 + lg*8];
      o = __builtin_amdgcn_mfma_f32_16x16x32_bf16(a, bb, o, 0,0,0);
    }
    size_t rb = ((size_t)wt*144 + wv*16 + lg*4)*192 + head*32 + ct2*16 + lr;
    #pragma unroll
    for (int r=0;r<4;r++) outp[rb + (size_t)r*192] = f2b(o[r]);
  }
}

// un-window (+unroll +crop) + LN + residual
__global__ __launch_bounds__(256) void unwin_ln(
  const unsigned short* __restrict__ ywin,
  const float* __restrict__ xsrc,
  const float* __restrict__ g, const float* __restrict__ bb,
  float* __restrict__ outf, unsigned short* __restrict__ outb, int roll)
{
  int tok = blockIdx.x*4 + (threadIdx.x>>6);
  if (tok >= NTOK) return;
  int lane = threadIdx.x & 63;
  int z = tok / (91*180);
  int rem = tok % (91*180);
  int h = rem / 180, wc = rem % 180;
  int zz=z, hh=h, ww=wc;
  if (roll){ zz = (z+7)&7; hh = (h+93)%96; ww = (wc+174)%180; }
  int nz = zz>>1, wz = zz&1;
  int nh = hh/6,  wh = hh%6;
  int nw = ww/12, w2 = ww%12;
  size_t row = ((size_t)(nw*64 + nz*16 + nh))*144 + wz*72 + wh*12 + w2;
  const unsigned short* yr = ywin + row*192;
  float v[3]; float s=0.f, ss=0.f;
  #pragma unroll
  for (int i=0;i<3;i++){ v[i] = b2f(yr[lane + i*64]); s += v[i]; ss += v[i]*v[i]; }
  #pragma unroll
  for (int off=32; off>=1; off>>=1){ s += __shfl_xor(s, off); ss += __shfl_xor(ss, off); }
  float mean = s * (1.0f/192.0f);
  float var = ss * (1.0f/192.0f) - mean*mean;
  float rinv = rsqrtf(var + 1e-5f);
  size_t tb = (size_t)tok*192;
  #pragma unroll
  for (int i=0;i<3;i++){
    int d = lane + i*64;
    float o = xsrc[tb + d] + ((v[i]-mean)*rinv*g[d] + bb[d]);
    outf[tb+d] = o;
    outb[tb+d] = f2b(o);
  }
}

// fused MLP + final LN + residual: out = xmid + LN( gelu(A@W1+b1) @ W2 + b2 )
// 128 rows/block, 4 waves x 32 rows; WEIGHTS STREAMED FROM GLOBAL (L1/L2-served),
// Hs wave-private, NO loop barriers.
__global__ __launch_bounds__(256) void mlp_fused_ln(
    const unsigned short* __restrict__ A,    // [M][192] bf16
    const unsigned short* __restrict__ W1t,  // [768][192]
    const float* __restrict__ bias1,         // [768]
    const unsigned short* __restrict__ W2t,  // [192][768]
    const float* __restrict__ mbias2,        // [192]
    const float* __restrict__ xmid,          // [M][192] f32
    const float* __restrict__ lng,           // [192]
    const float* __restrict__ lnb,           // [192]
    float* __restrict__ outF,                // [M][192] f32
    int M)
{
  __shared__ unsigned short Hs[4][32][40];
  __shared__ float b1s[768];
  __shared__ float eps[576];                // [mb2 | lng | lnb]
  int m0 = blockIdx.x*128;
  int t = threadIdx.x, lane = t & 63, w = t >> 6;
  int lg = lane >> 4, lr = lane & 15;

  bf16x8 afrA[6], afrB[6];
  {
    int ra = m0 + w*32 + lr, rb = ra + 16;
    if (ra < M){
      const unsigned short* ap = A + (size_t)ra*192 + lg*8;
      #pragma unroll
      for (int ks=0; ks<6; ks++) afrA[ks] = *(const bf16x8*)(ap + ks*32);
    } else {
      #pragma unroll
      for (int ks=0; ks<6; ks++)
        #pragma unroll
        for (int j=0;j<8;j++) afrA[ks][j] = 0;
    }
    if (rb < M){
      const unsigned short* ap = A + (size_t)rb*192 + lg*8;
      #pragma unroll
      for (int ks=0; ks<6; ks++) afrB[ks] = *(const bf16x8*)(ap + ks*32);
    } else {
      #pragma unroll
      for (int ks=0; ks<6; ks++)
        #pragma unroll
        for (int j=0;j<8;j++) afrB[ks][j] = 0;
    }
  }

  b1s[t] = bias1[t];
  b1s[t + 256] = bias1[t + 256];
  b1s[t + 512] = bias1[t + 512];
  if (t < 192){ eps[t] = mbias2[t]; eps[192 + t] = lng[t]; eps[384 + t] = lnb[t]; }
  __syncthreads();   // once, for b1s/eps

  f32x4 accA[12], accB[12];
  #pragma unroll
  for (int i=0;i<12;i++){ accA[i] = (f32x4){0.f,0.f,0.f,0.f}; accB[i] = (f32x4){0.f,0.f,0.f,0.f}; }

  // per-lane weight base pointers (coalesced in 64B runs across lanes)
  const unsigned short* w1base = W1t + (size_t)(2*lr)*192 + lg*8;        // + hc*192, +192 for odd row
  const unsigned short* w2base = W2t + (size_t)(2*lr)*768 + lg*8;        // + f*32*768, + hc

  for (int it=0; it<24; ++it){
    int hc = it*32;
    const unsigned short* w1p = w1base + (size_t)hc*192;

    f32x4 h0a = (f32x4){0.f,0.f,0.f,0.f}, h1a = h0a, h0b = h0a, h1b = h0a;
    #pragma unroll
    for (int ks=0; ks<6; ks++){
      bf16x8 b0  = *(const bf16x8*)(w1p + ks*32);
      bf16x8 b1f = *(const bf16x8*)(w1p + 192 + ks*32);
      h0a = __builtin_amdgcn_mfma_f32_16x16x32_bf16(afrA[ks], b0,  h0a, 0,0,0);
      h1a = __builtin_amdgcn_mfma_f32_16x16x32_bf16(afrA[ks], b1f, h1a, 0,0,0);
      h0b = __builtin_amdgcn_mfma_f32_16x16x32_bf16(afrB[ks], b0,  h0b, 0,0,0);
      h1b = __builtin_amdgcn_mfma_f32_16x16x32_bf16(afrB[ks], b1f, h1b, 0,0,0);
    }

    // issue W2 loads early (independent of gelu chain)
    bf16x8 c0v[6], c1v[6];
    #pragma unroll
    for (int f=0; f<6; f++){
      const unsigned short* w2p = w2base + (size_t)(f*32)*768 + hc;
      c0v[f] = *(const bf16x8*)(w2p);
      c1v[f] = *(const bf16x8*)(w2p + 768);
    }

    float bb0 = b1s[hc + 2*lr];
    float bb1 = b1s[hc + 2*lr + 1];
    #pragma unroll
    for (int r=0;r<4;r++){
      *(unsigned*)&Hs[w][lg*4 + r][2*lr] =
          pk_bf16(gelu_fast(h0a[r] + bb0), gelu_fast(h1a[r] + bb1));
      *(unsigned*)&Hs[w][16 + lg*4 + r][2*lr] =
          pk_bf16(gelu_fast(h0b[r] + bb0), gelu_fast(h1b[r] + bb1));
    }
    bf16x8 paA = *(const bf16x8*)&Hs[w][lr][lg*8];       // wave-private: lgkmcnt orders
    bf16x8 paB = *(const bf16x8*)&Hs[w][16 + lr][lg*8];

    #pragma unroll
    for (int f=0; f<6; f++){
      accA[2*f]   = __builtin_amdgcn_mfma_f32_16x16x32_bf16(paA, c0v[f], accA[2*f],   0,0,0);
      accA[2*f+1] = __builtin_amdgcn_mfma_f32_16x16x32_bf16(paA, c1v[f], accA[2*f+1], 0,0,0);
      accB[2*f]   = __builtin_amdgcn_mfma_f32_16x16x32_bf16(paB, c0v[f], accB[2*f],   0,0,0);
      accB[2*f+1] = __builtin_amdgcn_mfma_f32_16x16x32_bf16(paB, c1v[f], accB[2*f+1], 0,0,0);
    }
  }

  #pragma unroll
  for (int gsel=0; gsel<2; gsel++){
    f32x4* acc = gsel ? accB : accA;
    #pragma unroll
    for (int r=0;r<4;r++){
      int row = m0 + w*32 + gsel*16 + lg*4 + r;
      float s = 0.f, ss = 0.f;
      #pragma unroll
      for (int f=0; f<6; f++){
        float v0 = acc[2*f][r]   + eps[f*32 + 2*lr];
        float v1 = acc[2*f+1][r] + eps[f*32 + 2*lr + 1];
        s += v0 + v1; ss += v0*v0 + v1*v1;
      }
      #pragma unroll
      for (int off=1; off<16; off<<=1){ s += __shfl_xor(s, off); ss += __shfl_xor(ss, off); }
      float mean = s * (1.0f/192.0f);
      float var  = ss * (1.0f/192.0f) - mean*mean;
      float rinv = rsqrtf(var + 1e-5f);
      if (row < M){
        size_t base = (size_t)row*192;
        #pragma unroll
        for (int f=0; f<6; f++){
          int c0 = f*32 + 2*lr;
          float v0 = acc[2*f][r]   + eps[c0];
          float v1 = acc[2*f+1][r] + eps[c0 + 1];
          f32x2 xm = *(const f32x2*)&xmid[base + c0];
          f32x2 o;
          o[0] = xm[0] + (v0 - mean)*rinv*eps[192 + c0]     + eps[384 + c0];
          o[1] = xm[1] + (v1 - mean)*rinv*eps[192 + c0 + 1] + eps[384 + c0 + 1];
          *(f32x2*)&outF[base + c0] = o;
        }
      }
    }
  }
}

extern "C" void kernel_launch(void* const* d_in, const int* in_sizes, int n_in,
                              void* d_out, int out_size, void* d_ws, size_t ws_size,
                              hipStream_t stream)
{
  const float* x_in    = (const float*)d_in[0];
  const float* qkvw    = (const float*)d_in[1];
  const float* qkvbias = (const float*)d_in[2];
  const float* projw   = (const float*)d_in[3];
  const float* projbias= (const float*)d_in[4];
  const float* btab    = (const float*)d_in[5];
  const float* n1g = (const float*)d_in[6];
  const float* n1b = (const float*)d_in[7];
  const float* n2g = (const float*)d_in[8];
  const float* n2b = (const float*)d_in[9];
  const float* w1  = (const float*)d_in[10];
  const float* b1  = (const float*)d_in[11];
  const float* w2  = (const float*)d_in[12];
  const float* b2  = (const float*)d_in[13];
  float* outp = (float*)d_out;

  const size_t REG_A = (size_t)NTOKW*192;
  const size_t REG_B = (size_t)NTOKW*576;
  const size_t W_QT  = (size_t)2*576*192;
  const size_t W_PT  = (size_t)2*192*192;
  const size_t W_1T  = (size_t)2*768*192;
  const size_t W_2T  = (size_t)2*192*768;
  const size_t TOT_SH = REG_A + REG_B + W_QT + W_PT + W_1T + W_2T;
  const size_t NEEDED = TOT_SH*2 + (size_t)NTOK*192*4;
  if (ws_size < NEEDED) return;

  unsigned short* ws16 = (unsigned short*)d_ws;
  size_t off = 0;
  unsigned short* regA = ws16 + off; off += REG_A;   // xw / attn-out / xmidb
  unsigned short* regB = ws16 + off; off += REG_B;   // qkv-out / ywin
  unsigned short* wqt  = ws16 + off; off += W_QT;
  unsigned short* wpt  = ws16 + off; off += W_PT;
  unsigned short* w1t  = ws16 + off; off += W_1T;
  unsigned short* w2t  = ws16 + off; off += W_2T;
  float* xmidf = (float*)(ws16 + off);
  unsigned short* bw = (unsigned short*)xmidf;   // alias: dead before unwin_ln writes xmidf

  for (int dep=0; dep<2; dep++){
    transp<<<(192*576+255)/256,256,0,stream>>>(qkvw + (size_t)dep*192*576,
                                               wqt + (size_t)dep*576*192, 192, 576);
    transp<<<(192*192+255)/256,256,0,stream>>>(projw + (size_t)dep*192*192,
                                               wpt + (size_t)dep*192*192, 192, 192);
    transp<<<(192*768+255)/256,256,0,stream>>>(w1 + (size_t)dep*192*768,
                                               w1t + (size_t)dep*768*192, 192, 768);
    transp<<<(768*192+255)/256,256,0,stream>>>(w2 + (size_t)dep*768*192,
                                               w2t + (size_t)dep*192*768, 768, 192);
  }

  for (int dep=0; dep<2; dep++){
    int roll = dep;
    const float* xs = (dep==0) ? x_in : outp;
    float* xout = outp;

    gather_win<<<NTOKW*24/256, 256, 0, stream>>>(xs, regA, roll);

    dim3 g1(NTOKW/128, 3);     // N=576
    gemm_k192<<<g1, 512, 0, stream>>>(regA, wqt + (size_t)dep*576*192,
                                      qkvbias + dep*576, regB, 576);

    bias_pre<<<(384*9*64*40)/256, 256, 0, stream>>>(btab + (size_t)dep*3312*384, bw, roll);

    attn_win<<<960*6, 576, 0, stream>>>(regB, bw, regA);

    dim3 g2(NTOKW/128, 1);     // N=192
    gemm_k192<<<g2, 512, 0, stream>>>(regA, wpt + (size_t)dep*192*192,
                                      projbias + dep*192, regB, 192);

    unwin_ln<<<NTOK/4, 256, 0, stream>>>(regB, xs, n1g + dep*192, n1b + dep*192,
                                         xmidf, regA, roll);

    mlp_fused_ln<<<(NTOK+127)/128, 256, 0, stream>>>(
        regA, w1t + (size_t)dep*768*192, b1 + dep*768,
        w2t + (size_t)dep*192*768, b2 + dep*192,
        xmidf, n2g + dep*192, n2b + dep*192, xout, NTOK);
  }
}

// Round 15
// 1051.286 us; speedup vs baseline: 1.3289x; 1.3289x over previous
//
#include <hip/hip_runtime.h>
#include <math.h>

#define NTOK   131040   // 8*91*180
#define NTOKW  138240   // 15*64*144

typedef __attribute__((ext_vector_type(8))) short bf16x8;
typedef __attribute__((ext_vector_type(8))) unsigned short u16x8;
typedef __attribute__((ext_vector_type(4))) float f32x4;
typedef __attribute__((ext_vector_type(2))) float f32x2;

__device__ __forceinline__ float b2f(unsigned short u){
  union { unsigned u; float f; } v; v.u = ((unsigned)u) << 16; return v.f;
}
__device__ __forceinline__ unsigned short f2b(float f){
  union { float f; unsigned u; } v; v.f = f;
  unsigned r = v.u + 0x7FFFu + ((v.u >> 16) & 1u);
  return (unsigned short)(r >> 16);
}
// tanh-GELU via rcpf (no f32 div sequence); |err vs erf-GELU| ~3e-4
__device__ __forceinline__ float gelu_fast(float x){
  float t = 0.79788456080286536f * (x + 0.044715f * x * x * x);
  float e = __expf(2.0f * t);
  float th = 1.0f - 2.0f * __builtin_amdgcn_rcpf(e + 1.0f);
  return 0.5f * x * (1.0f + th);
}
__device__ __forceinline__ unsigned pk_bf16(float lo, float hi){
  unsigned r;
  asm("v_cvt_pk_bf16_f32 %0, %1, %2" : "=v"(r) : "v"(lo), "v"(hi));
  return r;
}
__device__ __forceinline__ void lds_barrier(){
  asm volatile("s_waitcnt lgkmcnt(0)" ::: "memory");
  __builtin_amdgcn_sched_barrier(0);
  __builtin_amdgcn_s_barrier();
  __builtin_amdgcn_sched_barrier(0);
}

// transpose-cast: dst[n][k] = (bf16)src[k][n]
__global__ __launch_bounds__(256) void transp(const float* __restrict__ src,
                                              unsigned short* __restrict__ dst,
                                              int K, int N){
  int i = blockIdx.x*256 + threadIdx.x;
  if (i < K*N){
    int n = i / K, k = i % K;
    dst[i] = f2b(src[(size_t)k*N + n]);
  }
}

// precompute bias+mask in MFMA-fragment layout; ONE u16x8 store per thread.
// bw[(((slice*9 + wv)*5 + vec)*64 + lane)*8 + elem], e = vec*8+elem = ct*4+r (<36)
__global__ __launch_bounds__(256) void bias_pre(
    const float* __restrict__ btab,
    unsigned short* __restrict__ bw,
    int roll)
{
  int gid = blockIdx.x*256 + threadIdx.x;   // < 384*9*5*64
  int lane = gid & 63;
  int rem  = gid >> 6;
  int vec  = rem % 5;
  int rem2 = rem / 5;
  int wv   = rem2 % 9;
  int slice= rem2 / 9;
  int tw = slice / 6, head = slice % 6;
  int nz = tw >> 4, nh = tw & 15;
  u16x8 out;
  #pragma unroll
  for (int elem=0; elem<8; elem++){
    int e = vec*8 + elem;
    unsigned short o = 0;
    if (e < 36){
      int ct = e >> 2, r = e & 3;
      int i = wv*16 + (lane>>4)*4 + r;
      int j = ct*16 + (lane & 15);
      int ia = i/72, ib = (i%72)/12, ic = i%12;
      int ja = j/72, jb = (j%72)/12, jc = j%12;
      int idx = (ia + 2*ja)*828 + (ib + 6*jb)*23 + (ic - jc + 11);
      float v = btab[(size_t)idx*384 + slice];
      if (roll){
        int zi = nz*2+ia, hi = nh*6+ib, zj = nz*2+ja, hj = nh*6+jb;
        int ri = 3*((zi<6)?0:((zi<7)?1:2)) + ((hi<90)?0:((hi<93)?1:2));
        int rj = 3*((zj<6)?0:((zj<7)?1:2)) + ((hj<90)?0:((hj<93)?1:2));
        if (ri != rj) v -= 100.0f;
      }
      o = f2b(v);
    }
    out[elem] = o;
  }
  *(u16x8*)(bw + (size_t)gid*8) = out;
}

// window-partition gather (+pad +roll), fp32 -> bf16
__global__ __launch_bounds__(256) void gather_win(const float* __restrict__ x,
                                                  unsigned short* __restrict__ xw,
                                                  int roll){
  int gid = blockIdx.x*256 + threadIdx.x;
  int row = gid / 24;
  int dp  = gid % 24;
  int tok = row % 144;
  int wt  = row / 144;
  int tw  = wt & 63;
  int w   = wt >> 6;
  int nz = tw >> 4, nh = tw & 15;
  int wz = tok / 72; int rem = tok % 72; int wh = rem / 12; int ww = rem % 12;
  int z = nz*2 + wz, h = nh*6 + wh, wc = w*12 + ww;
  if (roll){ z = (z+1)&7; h = (h+3)%96; wc = (wc+6)%180; }
  int d0 = dp*8;
  u16x8 o;
  if (h < 91){
    const float* s = x + ((size_t)((z*91 + h)*180 + wc))*192 + d0;
    #pragma unroll
    for (int i=0;i<8;i++) o[i] = f2b(s[i]);
  } else {
    #pragma unroll
    for (int i=0;i<8;i++) o[i] = 0;
  }
  *(u16x8*)(xw + (size_t)row*192 + d0) = o;
}

// K=192 GEMM: C[M x N] = A[M x 192] @ Bt[N x 192]^T + bias
__global__ __launch_bounds__(512) void gemm_k192(
    const unsigned short* __restrict__ A,
    const unsigned short* __restrict__ Bt,
    const float* __restrict__ bias,
    unsigned short* __restrict__ C,
    int N)
{
  __shared__ unsigned short Bst[192][200];
  int m0 = blockIdx.x * 128;
  int n0 = blockIdx.y * 192;
  int t = threadIdx.x;
  int lane = t & 63, w = t >> 6;
  int wm = w >> 2, wn = w & 3;
  int lg = lane >> 4, lr = lane & 15;

  #pragma unroll
  for (int i=0;i<9;i++){
    int idx = t + i*512;
    int r = idx / 24, c = (idx % 24)*8;
    *(u16x8*)&Bst[r][c] = *(const u16x8*)(Bt + (size_t)(n0 + r)*192 + c);
  }
  __syncthreads();

  const unsigned short* aRow = A + (size_t)(m0 + wm*64 + lr)*192 + lg*8;

  f32x4 acc[4][3];
  #pragma unroll
  for (int a=0;a<4;a++)
    #pragma unroll
    for (int b=0;b<3;b++) acc[a][b] = (f32x4){0.f,0.f,0.f,0.f};

  bf16x8 aP[2][6];
  #pragma unroll
  for (int ks=0; ks<6; ks++) aP[0][ks] = *(const bf16x8*)(aRow + ks*32);

  #pragma unroll
  for (int rt=0; rt<4; rt++){
    if (rt < 3){
      const unsigned short* an = aRow + (size_t)(rt+1)*16*192;
      #pragma unroll
      for (int ks=0; ks<6; ks++) aP[(rt+1)&1][ks] = *(const bf16x8*)(an + ks*32);
    }
    #pragma unroll
    for (int ks=0; ks<6; ks++){
      bf16x8 b0 = *(const bf16x8*)&Bst[wn*48 +      lr][ks*32 + lg*8];
      bf16x8 b1 = *(const bf16x8*)&Bst[wn*48 + 16 + lr][ks*32 + lg*8];
      bf16x8 b2 = *(const bf16x8*)&Bst[wn*48 + 32 + lr][ks*32 + lg*8];
      bf16x8 af = aP[rt&1][ks];
      acc[rt][0] = __builtin_amdgcn_mfma_f32_16x16x32_bf16(af, b0, acc[rt][0], 0,0,0);
      acc[rt][1] = __builtin_amdgcn_mfma_f32_16x16x32_bf16(af, b1, acc[rt][1], 0,0,0);
      acc[rt][2] = __builtin_amdgcn_mfma_f32_16x16x32_bf16(af, b2, acc[rt][2], 0,0,0);
    }
  }

  #pragma unroll
  for (int rt=0; rt<4; rt++){
    #pragma unroll
    for (int fn=0; fn<3; fn++){
      int colg = n0 + wn*48 + fn*16 + lr;
      float bv = bias[colg];
      #pragma unroll
      for (int r=0;r<4;r++){
        int rowg = m0 + wm*64 + rt*16 + lg*4 + r;
        C[(size_t)rowg*N + colg] = f2b(acc[rt][fn][r] + bv);
      }
    }
  }
}

// fused windowed attention: one block per (window-pair, head). 9 waves.
// bias via fragment-layout table: 5 coalesced u16x8 loads per lane.
__global__ __launch_bounds__(576) void attn_win(
    const unsigned short* __restrict__ qkv,
    const unsigned short* __restrict__ bw,
    unsigned short* __restrict__ outp)
{
  __shared__ union {
    struct { unsigned short Qs[144][32]; unsigned short Ks[144][40]; } qk;
    unsigned short Ps[144][160];
  } U;
  __shared__ unsigned short Vst[32][160];

  int b = blockIdx.x;
  int head = b % 6;
  int wt = b / 6;
  int tw = wt & 63;
  int t = threadIdx.x;
  int lane = t & 63;
  int wv = t >> 6;
  int lg = lane >> 4, lr = lane & 15;

  {
    int tok = t >> 2, c0 = (t & 3)*8;
    size_t base = ((size_t)wt*144 + tok)*576 + head*32 + c0;
    u16x8 qv = *(const u16x8*)(qkv + base);
    u16x8 kv = *(const u16x8*)(qkv + base + 192);
    u16x8 vv = *(const u16x8*)(qkv + base + 384);
    u16x8 qs;
    #pragma unroll
    for (int i=0;i<8;i++) qs[i] = f2b(b2f(qv[i]) * 0.17677669529663687f);
    *(u16x8*)&U.qk.Qs[tok][c0] = qs;
    *(u16x8*)&U.qk.Ks[tok][c0] = kv;
    #pragma unroll
    for (int i=0;i<8;i++) Vst[c0+i][tok] = vv[i];
  }
  if (t < 512) Vst[t >> 4][144 + (t & 15)] = 0;

  u16x8 bv0, bv1, bv2, bv3, bv4;
  {
    size_t sbase = ((((size_t)(tw*6 + head))*9 + wv)*5*64 + lane)*8;
    bv0 = *(const u16x8*)(bw + sbase);
    bv1 = *(const u16x8*)(bw + sbase + 64*8);
    bv2 = *(const u16x8*)(bw + sbase + 2*64*8);
    bv3 = *(const u16x8*)(bw + sbase + 3*64*8);
    bv4 = *(const u16x8*)(bw + sbase + 4*64*8);
  }
  __syncthreads();

  float s[9][4];
  {
    bf16x8 a = *(const bf16x8*)&U.qk.Qs[wv*16 + lr][lg*8];
    #pragma unroll
    for (int ct=0; ct<9; ct++){
      bf16x8 bb = *(const bf16x8*)&U.qk.Ks[ct*16 + lr][lg*8];
      f32x4 d = {0.f,0.f,0.f,0.f};
      d = __builtin_amdgcn_mfma_f32_16x16x32_bf16(a, bb, d, 0,0,0);
      s[ct][0]=d[0]; s[ct][1]=d[1]; s[ct][2]=d[2]; s[ct][3]=d[3];
    }
  }

  #pragma unroll
  for (int ct=0; ct<9; ct++){
    #pragma unroll
    for (int r=0;r<4;r++){
      const int e = ct*4 + r;
      unsigned short bu =
        (e < 8)  ? bv0[e & 7] :
        (e < 16) ? bv1[e & 7] :
        (e < 24) ? bv2[e & 7] :
        (e < 32) ? bv3[e & 7] : bv4[e & 7];
      s[ct][r] += b2f(bu);
    }
  }

  float mx[4] = {-1e30f,-1e30f,-1e30f,-1e30f};
  #pragma unroll
  for (int ct=0; ct<9; ct++)
    #pragma unroll
    for (int r=0;r<4;r++) mx[r] = fmaxf(mx[r], s[ct][r]);
  #pragma unroll
  for (int off=1; off<16; off<<=1)
    #pragma unroll
    for (int r=0;r<4;r++) mx[r] = fmaxf(mx[r], __shfl_xor(mx[r], off));
  float sm[4] = {0.f,0.f,0.f,0.f};
  #pragma unroll
  for (int ct=0; ct<9; ct++)
    #pragma unroll
    for (int r=0;r<4;r++){ s[ct][r] = __expf(s[ct][r] - mx[r]); sm[r] += s[ct][r]; }
  #pragma unroll
  for (int off=1; off<16; off<<=1)
    #pragma unroll
    for (int r=0;r<4;r++) sm[r] += __shfl_xor(sm[r], off);
  float inv[4];
  #pragma unroll
  for (int r=0;r<4;r++) inv[r] = 1.0f / sm[r];

  lds_barrier();

  #pragma unroll
  for (int ct=0; ct<9; ct++)
    #pragma unroll
    for (int r=0;r<4;r++)
      U.Ps[wv*16 + lg*4 + r][ct*16 + lr] = f2b(s[ct][r] * inv[r]);
  #pragma unroll
  for (int r=0;r<4;r++) U.Ps[wv*16 + lg*4 + r][144 + lr] = 0;
  __syncthreads();

  #pragma unroll
  for (int ct2=0; ct2<2; ct2++){
    f32x4 o = {0.f,0.f,0.f,0.f};
    #pragma unroll
    for (int kt=0; kt<5; kt++){
      bf16x8 a  = *(const bf16x8*)&U.Ps[wv*16 + lr][kt*32 + lg*8];
      bf16x8 bb = *(const bf16x8*)&Vst[ct2*16 + lr][kt*32 + lg*8];
      o = __builtin_amdgcn_mfma_f32_16x16x32_bf16(a, bb, o, 0,0,0);
    }
    size_t rb = ((size_t)wt*144 + wv*16 + lg*4)*192 + head*32 + ct2*16 + lr;
    #pragma unroll
    for (int r=0;r<4;r++) outp[rb + (size_t)r*192] = f2b(o[r]);
  }
}

// un-window (+unroll +crop) + LN + residual
__global__ __launch_bounds__(256) void unwin_ln(
  const unsigned short* __restrict__ ywin,
  const float* __restrict__ xsrc,
  const float* __restrict__ g, const float* __restrict__ bb,
  float* __restrict__ outf, unsigned short* __restrict__ outb, int roll)
{
  int tok = blockIdx.x*4 + (threadIdx.x>>6);
  if (tok >= NTOK) return;
  int lane = threadIdx.x & 63;
  int z = tok / (91*180);
  int rem = tok % (91*180);
  int h = rem / 180, wc = rem % 180;
  int zz=z, hh=h, ww=wc;
  if (roll){ zz = (z+7)&7; hh = (h+93)%96; ww = (wc+174)%180; }
  int nz = zz>>1, wz = zz&1;
  int nh = hh/6,  wh = hh%6;
  int nw = ww/12, w2 = ww%12;
  size_t row = ((size_t)(nw*64 + nz*16 + nh))*144 + wz*72 + wh*12 + w2;
  const unsigned short* yr = ywin + row*192;
  float v[3]; float s=0.f, ss=0.f;
  #pragma unroll
  for (int i=0;i<3;i++){ v[i] = b2f(yr[lane + i*64]); s += v[i]; ss += v[i]*v[i]; }
  #pragma unroll
  for (int off=32; off>=1; off>>=1){ s += __shfl_xor(s, off); ss += __shfl_xor(ss, off); }
  float mean = s * (1.0f/192.0f);
  float var = ss * (1.0f/192.0f) - mean*mean;
  float rinv = rsqrtf(var + 1e-5f);
  size_t tb = (size_t)tok*192;
  #pragma unroll
  for (int i=0;i<3;i++){
    int d = lane + i*64;
    float o = xsrc[tb + d] + ((v[i]-mean)*rinv*g[d] + bb[d]);
    outf[tb+d] = o;
    outb[tb+d] = f2b(o);
  }
}

// fused MLP + final LN + residual: out = xmid + LN( gelu(A@W1+b1) @ W2 + b2 )
// 256 rows/block, 8 waves x 32 rows; double-buffered weight chunks, 1 barrier/iter.
__global__ __launch_bounds__(512) void mlp_fused_ln(
    const unsigned short* __restrict__ A,    // [M][192] bf16
    const unsigned short* __restrict__ W1t,  // [768][192]
    const float* __restrict__ bias1,         // [768]
    const unsigned short* __restrict__ W2t,  // [192][768]
    const float* __restrict__ mbias2,        // [192]
    const float* __restrict__ xmid,          // [M][192] f32
    const float* __restrict__ lng,           // [192]
    const float* __restrict__ lnb,           // [192]
    float* __restrict__ outF,                // [M][192] f32
    int M)
{
  __shared__ unsigned short W1s[2][32][196];
  __shared__ unsigned short W2s[2][192][44];
  __shared__ unsigned short Hs[8][32][40];
  __shared__ float b1s[768];
  __shared__ float eps[576];                // [mb2 | lng | lnb]
  int m0 = blockIdx.x*256;
  int t = threadIdx.x, lane = t & 63, w = t >> 6;
  int lg = lane >> 4, lr = lane & 15;

  bf16x8 afrA[6], afrB[6];
  {
    int ra = m0 + w*32 + lr, rb = ra + 16;
    if (ra < M){
      const unsigned short* ap = A + (size_t)ra*192 + lg*8;
      #pragma unroll
      for (int ks=0; ks<6; ks++) afrA[ks] = *(const bf16x8*)(ap + ks*32);
    } else {
      #pragma unroll
      for (int ks=0; ks<6; ks++)
        #pragma unroll
        for (int j=0;j<8;j++) afrA[ks][j] = 0;
    }
    if (rb < M){
      const unsigned short* ap = A + (size_t)rb*192 + lg*8;
      #pragma unroll
      for (int ks=0; ks<6; ks++) afrB[ks] = *(const bf16x8*)(ap + ks*32);
    } else {
      #pragma unroll
      for (int ks=0; ks<6; ks++)
        #pragma unroll
        for (int j=0;j<8;j++) afrB[ks][j] = 0;
    }
  }

  b1s[t] = bias1[t];
  if (t < 256) b1s[512 + t] = bias1[512 + t];
  if (t < 192){ eps[t] = mbias2[t]; eps[192 + t] = lng[t]; eps[384 + t] = lnb[t]; }

  int i1r[2], i1c[2], i2r[2], i2c[2];
  #pragma unroll
  for (int i=0;i<2;i++){
    int idx = t + i*512;
    i1r[i] = idx/24; i1c[i] = (idx%24)*8;
    i2r[i] = idx/4;  i2c[i] = (idx&3)*8;
  }
  bool g2nd = (t + 512) < 768;

  {
    u16x8 a0 = *(const u16x8*)(W1t + (size_t)i1r[0]*192 + i1c[0]);
    u16x8 b0 = *(const u16x8*)(W2t + (size_t)i2r[0]*768 + i2c[0]);
    *(u16x8*)&W1s[0][i1r[0]][i1c[0]] = a0;
    *(u16x8*)&W2s[0][i2r[0]][i2c[0]] = b0;
    if (g2nd){
      u16x8 a1 = *(const u16x8*)(W1t + (size_t)i1r[1]*192 + i1c[1]);
      u16x8 b1v = *(const u16x8*)(W2t + (size_t)i2r[1]*768 + i2c[1]);
      *(u16x8*)&W1s[0][i1r[1]][i1c[1]] = a1;
      *(u16x8*)&W2s[0][i2r[1]][i2c[1]] = b1v;
    }
  }
  lds_barrier();

  f32x4 accA[12], accB[12];
  #pragma unroll
  for (int i=0;i<12;i++){ accA[i] = (f32x4){0.f,0.f,0.f,0.f}; accB[i] = (f32x4){0.f,0.f,0.f,0.f}; }

  u16x8 w1r[2], w2r[2];

  for (int it=0; it<24; ++it){
    int cur = it & 1;
    if (it < 23){
      int hc2 = (it+1)*32;
      w1r[0] = *(const u16x8*)(W1t + (size_t)(hc2 + i1r[0])*192 + i1c[0]);
      w2r[0] = *(const u16x8*)(W2t + (size_t)i2r[0]*768 + hc2 + i2c[0]);
      if (g2nd){
        w1r[1] = *(const u16x8*)(W1t + (size_t)(hc2 + i1r[1])*192 + i1c[1]);
        w2r[1] = *(const u16x8*)(W2t + (size_t)i2r[1]*768 + hc2 + i2c[1]);
      }
    }

    int hc = it*32;
    f32x4 h0a = (f32x4){0.f,0.f,0.f,0.f}, h1a = h0a, h0b = h0a, h1b = h0a;
    #pragma unroll
    for (int ks=0; ks<6; ks++){
      bf16x8 b0  = *(const bf16x8*)&W1s[cur][2*lr    ][ks*32 + lg*8];
      bf16x8 b1f = *(const bf16x8*)&W1s[cur][2*lr + 1][ks*32 + lg*8];
      h0a = __builtin_amdgcn_mfma_f32_16x16x32_bf16(afrA[ks], b0,  h0a, 0,0,0);
      h1a = __builtin_amdgcn_mfma_f32_16x16x32_bf16(afrA[ks], b1f, h1a, 0,0,0);
      h0b = __builtin_amdgcn_mfma_f32_16x16x32_bf16(afrB[ks], b0,  h0b, 0,0,0);
      h1b = __builtin_amdgcn_mfma_f32_16x16x32_bf16(afrB[ks], b1f, h1b, 0,0,0);
    }
    float bb0 = b1s[hc + 2*lr];
    float bb1 = b1s[hc + 2*lr + 1];
    #pragma unroll
    for (int r=0;r<4;r++){
      *(unsigned*)&Hs[w][lg*4 + r][2*lr] =
          pk_bf16(gelu_fast(h0a[r] + bb0), gelu_fast(h1a[r] + bb1));
      *(unsigned*)&Hs[w][16 + lg*4 + r][2*lr] =
          pk_bf16(gelu_fast(h0b[r] + bb0), gelu_fast(h1b[r] + bb1));
    }
    bf16x8 paA = *(const bf16x8*)&Hs[w][lr][lg*8];
    bf16x8 paB = *(const bf16x8*)&Hs[w][16 + lr][lg*8];
    #pragma unroll
    for (int f=0; f<6; f++){
      bf16x8 c0 = *(const bf16x8*)&W2s[cur][f*32 + 2*lr    ][lg*8];
      bf16x8 c1 = *(const bf16x8*)&W2s[cur][f*32 + 2*lr + 1][lg*8];
      accA[2*f]   = __builtin_amdgcn_mfma_f32_16x16x32_bf16(paA, c0, accA[2*f],   0,0,0);
      accA[2*f+1] = __builtin_amdgcn_mfma_f32_16x16x32_bf16(paA, c1, accA[2*f+1], 0,0,0);
      accB[2*f]   = __builtin_amdgcn_mfma_f32_16x16x32_bf16(paB, c0, accB[2*f],   0,0,0);
      accB[2*f+1] = __builtin_amdgcn_mfma_f32_16x16x32_bf16(paB, c1, accB[2*f+1], 0,0,0);
    }

    if (it < 23){
      int nxt = cur ^ 1;
      *(u16x8*)&W1s[nxt][i1r[0]][i1c[0]] = w1r[0];
      *(u16x8*)&W2s[nxt][i2r[0]][i2c[0]] = w2r[0];
      if (g2nd){
        *(u16x8*)&W1s[nxt][i1r[1]][i1c[1]] = w1r[1];
        *(u16x8*)&W2s[nxt][i2r[1]][i2c[1]] = w2r[1];
      }
    }
    lds_barrier();
  }

  #pragma unroll
  for (int gsel=0; gsel<2; gsel++){
    f32x4* acc = gsel ? accB : accA;
    #pragma unroll
    for (int r=0;r<4;r++){
      int row = m0 + w*32 + gsel*16 + lg*4 + r;
      float s = 0.f, ss = 0.f;
      #pragma unroll
      for (int f=0; f<6; f++){
        float v0 = acc[2*f][r]   + eps[f*32 + 2*lr];
        float v1 = acc[2*f+1][r] + eps[f*32 + 2*lr + 1];
        s += v0 + v1; ss += v0*v0 + v1*v1;
      }
      #pragma unroll
      for (int off=1; off<16; off<<=1){ s += __shfl_xor(s, off); ss += __shfl_xor(ss, off); }
      float mean = s * (1.0f/192.0f);
      float var  = ss * (1.0f/192.0f) - mean*mean;
      float rinv = rsqrtf(var + 1e-5f);
      if (row < M){
        size_t base = (size_t)row*192;
        #pragma unroll
        for (int f=0; f<6; f++){
          int c0 = f*32 + 2*lr;
          float v0 = acc[2*f][r]   + eps[c0];
          float v1 = acc[2*f+1][r] + eps[c0 + 1];
          f32x2 xm = *(const f32x2*)&xmid[base + c0];
          f32x2 o;
          o[0] = xm[0] + (v0 - mean)*rinv*eps[192 + c0]     + eps[384 + c0];
          o[1] = xm[1] + (v1 - mean)*rinv*eps[192 + c0 + 1] + eps[384 + c0 + 1];
          *(f32x2*)&outF[base + c0] = o;
        }
      }
    }
  }
}

extern "C" void kernel_launch(void* const* d_in, const int* in_sizes, int n_in,
                              void* d_out, int out_size, void* d_ws, size_t ws_size,
                              hipStream_t stream)
{
  const float* x_in    = (const float*)d_in[0];
  const float* qkvw    = (const float*)d_in[1];
  const float* qkvbias = (const float*)d_in[2];
  const float* projw   = (const float*)d_in[3];
  const float* projbias= (const float*)d_in[4];
  const float* btab    = (const float*)d_in[5];
  const float* n1g = (const float*)d_in[6];
  const float* n1b = (const float*)d_in[7];
  const float* n2g = (const float*)d_in[8];
  const float* n2b = (const float*)d_in[9];
  const float* w1  = (const float*)d_in[10];
  const float* b1  = (const float*)d_in[11];
  const float* w2  = (const float*)d_in[12];
  const float* b2  = (const float*)d_in[13];
  float* outp = (float*)d_out;

  const size_t REG_A = (size_t)NTOKW*192;
  const size_t REG_B = (size_t)NTOKW*576;
  const size_t W_QT  = (size_t)2*576*192;
  const size_t W_PT  = (size_t)2*192*192;
  const size_t W_1T  = (size_t)2*768*192;
  const size_t W_2T  = (size_t)2*192*768;
  const size_t TOT_SH = REG_A + REG_B + W_QT + W_PT + W_1T + W_2T;
  const size_t NEEDED = TOT_SH*2 + (size_t)NTOK*192*4;
  if (ws_size < NEEDED) return;

  unsigned short* ws16 = (unsigned short*)d_ws;
  size_t off = 0;
  unsigned short* regA = ws16 + off; off += REG_A;   // xw / attn-out / xmidb
  unsigned short* regB = ws16 + off; off += REG_B;   // qkv-out / ywin
  unsigned short* wqt  = ws16 + off; off += W_QT;
  unsigned short* wpt  = ws16 + off; off += W_PT;
  unsigned short* w1t  = ws16 + off; off += W_1T;
  unsigned short* w2t  = ws16 + off; off += W_2T;
  float* xmidf = (float*)(ws16 + off);
  unsigned short* bw = (unsigned short*)xmidf;   // alias: dead before unwin_ln writes xmidf

  for (int dep=0; dep<2; dep++){
    transp<<<(192*576+255)/256,256,0,stream>>>(qkvw + (size_t)dep*192*576,
                                               wqt + (size_t)dep*576*192, 192, 576);
    transp<<<(192*192+255)/256,256,0,stream>>>(projw + (size_t)dep*192*192,
                                               wpt + (size_t)dep*192*192, 192, 192);
    transp<<<(192*768+255)/256,256,0,stream>>>(w1 + (size_t)dep*192*768,
                                               w1t + (size_t)dep*768*192, 192, 768);
    transp<<<(768*192+255)/256,256,0,stream>>>(w2 + (size_t)dep*768*192,
                                               w2t + (size_t)dep*192*768, 768, 192);
  }

  for (int dep=0; dep<2; dep++){
    int roll = dep;
    const float* xs = (dep==0) ? x_in : outp;
    float* xout = outp;

    gather_win<<<NTOKW*24/256, 256, 0, stream>>>(xs, regA, roll);

    dim3 g1(NTOKW/128, 3);     // N=576
    gemm_k192<<<g1, 512, 0, stream>>>(regA, wqt + (size_t)dep*576*192,
                                      qkvbias + dep*576, regB, 576);

    bias_pre<<<(384*9*5*64)/256, 256, 0, stream>>>(btab + (size_t)dep*3312*384, bw, roll);

    attn_win<<<960*6, 576, 0, stream>>>(regB, bw, regA);

    dim3 g2(NTOKW/128, 1);     // N=192
    gemm_k192<<<g2, 512, 0, stream>>>(regA, wpt + (size_t)dep*192*192,
                                      projbias + dep*192, regB, 192);

    unwin_ln<<<NTOK/4, 256, 0, stream>>>(regB, xs, n1g + dep*192, n1b + dep*192,
                                         xmidf, regA, roll);

    mlp_fused_ln<<<(NTOK+255)/256, 512, 0, stream>>>(
        regA, w1t + (size_t)dep*768*192, b1 + dep*768,
        w2t + (size_t)dep*192*768, b2 + dep*192,
        xmidf, n2g + dep*192, n2b + dep*192, xout, NTOK);
  }
}

// Round 16
// 990.892 us; speedup vs baseline: 1.4099x; 1.0609x over previous
//
#include <hip/hip_runtime.h>
#include <math.h>

#define NTOK   131040   // 8*91*180
#define NTOKW  138240   // 15*64*144

typedef __attribute__((ext_vector_type(8))) short bf16x8;
typedef __attribute__((ext_vector_type(8))) unsigned short u16x8;
typedef __attribute__((ext_vector_type(4))) float f32x4;
typedef __attribute__((ext_vector_type(2))) float f32x2;

__device__ __forceinline__ float b2f(unsigned short u){
  union { unsigned u; float f; } v; v.u = ((unsigned)u) << 16; return v.f;
}
__device__ __forceinline__ unsigned short f2b(float f){
  union { float f; unsigned u; } v; v.f = f;
  unsigned r = v.u + 0x7FFFu + ((v.u >> 16) & 1u);
  return (unsigned short)(r >> 16);
}
// tanh-GELU via rcpf (no f32 div sequence); |err vs erf-GELU| ~3e-4
__device__ __forceinline__ float gelu_fast(float x){
  float t = 0.79788456080286536f * (x + 0.044715f * x * x * x);
  float e = __expf(2.0f * t);
  float th = 1.0f - 2.0f * __builtin_amdgcn_rcpf(e + 1.0f);
  return 0.5f * x * (1.0f + th);
}
__device__ __forceinline__ unsigned pk_bf16(float lo, float hi){
  unsigned r;
  asm("v_cvt_pk_bf16_f32 %0, %1, %2" : "=v"(r) : "v"(lo), "v"(hi));
  return r;
}
__device__ __forceinline__ void lds_barrier(){
  asm volatile("s_waitcnt lgkmcnt(0)" ::: "memory");
  __builtin_amdgcn_sched_barrier(0);
  __builtin_amdgcn_s_barrier();
  __builtin_amdgcn_sched_barrier(0);
}

// transpose-cast: dst[n][k] = (bf16)src[k][n]
__global__ __launch_bounds__(256) void transp(const float* __restrict__ src,
                                              unsigned short* __restrict__ dst,
                                              int K, int N){
  int i = blockIdx.x*256 + threadIdx.x;
  if (i < K*N){
    int n = i / K, k = i % K;
    dst[i] = f2b(src[(size_t)k*N + n]);
  }
}

// precompute bias+mask in MFMA-fragment layout; ONE u16x8 store per thread.
__global__ __launch_bounds__(256) void bias_pre(
    const float* __restrict__ btab,
    unsigned short* __restrict__ bw,
    int roll)
{
  int gid = blockIdx.x*256 + threadIdx.x;   // < 384*9*5*64
  int lane = gid & 63;
  int rem  = gid >> 6;
  int vec  = rem % 5;
  int rem2 = rem / 5;
  int wv   = rem2 % 9;
  int slice= rem2 / 9;
  int tw = slice / 6;
  int nz = tw >> 4, nh = tw & 15;
  u16x8 out;
  #pragma unroll
  for (int elem=0; elem<8; elem++){
    int e = vec*8 + elem;
    unsigned short o = 0;
    if (e < 36){
      int ct = e >> 2, r = e & 3;
      int i = wv*16 + (lane>>4)*4 + r;
      int j = ct*16 + (lane & 15);
      int ia = i/72, ib = (i%72)/12, ic = i%12;
      int ja = j/72, jb = (j%72)/12, jc = j%12;
      int idx = (ia + 2*ja)*828 + (ib + 6*jb)*23 + (ic - jc + 11);
      float v = btab[(size_t)idx*384 + slice];
      if (roll){
        int zi = nz*2+ia, hi = nh*6+ib, zj = nz*2+ja, hj = nh*6+jb;
        int ri = 3*((zi<6)?0:((zi<7)?1:2)) + ((hi<90)?0:((hi<93)?1:2));
        int rj = 3*((zj<6)?0:((zj<7)?1:2)) + ((hj<90)?0:((hj<93)?1:2));
        if (ri != rj) v -= 100.0f;
      }
      o = f2b(v);
    }
    out[elem] = o;
  }
  *(u16x8*)(bw + (size_t)gid*8) = out;
}

// window-partition gather (+pad +roll), fp32 -> bf16
__global__ __launch_bounds__(256) void gather_win(const float* __restrict__ x,
                                                  unsigned short* __restrict__ xw,
                                                  int roll){
  int gid = blockIdx.x*256 + threadIdx.x;
  int row = gid / 24;
  int dp  = gid % 24;
  int tok = row % 144;
  int wt  = row / 144;
  int tw  = wt & 63;
  int w   = wt >> 6;
  int nz = tw >> 4, nh = tw & 15;
  int wz = tok / 72; int rem = tok % 72; int wh = rem / 12; int ww = rem % 12;
  int z = nz*2 + wz, h = nh*6 + wh, wc = w*12 + ww;
  if (roll){ z = (z+1)&7; h = (h+3)%96; wc = (wc+6)%180; }
  int d0 = dp*8;
  u16x8 o;
  if (h < 91){
    const float* s = x + ((size_t)((z*91 + h)*180 + wc))*192 + d0;
    #pragma unroll
    for (int i=0;i<8;i++) o[i] = f2b(s[i]);
  } else {
    #pragma unroll
    for (int i=0;i<8;i++) o[i] = 0;
  }
  *(u16x8*)(xw + (size_t)row*192 + d0) = o;
}

// K=192 GEMM: C[M x N] = A[M x 192] @ Bt[N x 192]^T + bias
__global__ __launch_bounds__(512) void gemm_k192(
    const unsigned short* __restrict__ A,
    const unsigned short* __restrict__ Bt,
    const float* __restrict__ bias,
    unsigned short* __restrict__ C,
    int N)
{
  __shared__ unsigned short Bst[192][200];
  int m0 = blockIdx.x * 128;
  int n0 = blockIdx.y * 192;
  int t = threadIdx.x;
  int lane = t & 63, w = t >> 6;
  int wm = w >> 2, wn = w & 3;
  int lg = lane >> 4, lr = lane & 15;

  #pragma unroll
  for (int i=0;i<9;i++){
    int idx = t + i*512;
    int r = idx / 24, c = (idx % 24)*8;
    *(u16x8*)&Bst[r][c] = *(const u16x8*)(Bt + (size_t)(n0 + r)*192 + c);
  }
  __syncthreads();

  const unsigned short* aRow = A + (size_t)(m0 + wm*64 + lr)*192 + lg*8;

  f32x4 acc[4][3];
  #pragma unroll
  for (int a=0;a<4;a++)
    #pragma unroll
    for (int b=0;b<3;b++) acc[a][b] = (f32x4){0.f,0.f,0.f,0.f};

  bf16x8 aP[2][6];
  #pragma unroll
  for (int ks=0; ks<6; ks++) aP[0][ks] = *(const bf16x8*)(aRow + ks*32);

  #pragma unroll
  for (int rt=0; rt<4; rt++){
    if (rt < 3){
      const unsigned short* an = aRow + (size_t)(rt+1)*16*192;
      #pragma unroll
      for (int ks=0; ks<6; ks++) aP[(rt+1)&1][ks] = *(const bf16x8*)(an + ks*32);
    }
    #pragma unroll
    for (int ks=0; ks<6; ks++){
      bf16x8 b0 = *(const bf16x8*)&Bst[wn*48 +      lr][ks*32 + lg*8];
      bf16x8 b1 = *(const bf16x8*)&Bst[wn*48 + 16 + lr][ks*32 + lg*8];
      bf16x8 b2 = *(const bf16x8*)&Bst[wn*48 + 32 + lr][ks*32 + lg*8];
      bf16x8 af = aP[rt&1][ks];
      acc[rt][0] = __builtin_amdgcn_mfma_f32_16x16x32_bf16(af, b0, acc[rt][0], 0,0,0);
      acc[rt][1] = __builtin_amdgcn_mfma_f32_16x16x32_bf16(af, b1, acc[rt][1], 0,0,0);
      acc[rt][2] = __builtin_amdgcn_mfma_f32_16x16x32_bf16(af, b2, acc[rt][2], 0,0,0);
    }
  }

  #pragma unroll
  for (int rt=0; rt<4; rt++){
    #pragma unroll
    for (int fn=0; fn<3; fn++){
      int colg = n0 + wn*48 + fn*16 + lr;
      float bv = bias[colg];
      #pragma unroll
      for (int r=0;r<4;r++){
        int rowg = m0 + wm*64 + rt*16 + lg*4 + r;
        C[(size_t)rowg*N + colg] = f2b(acc[rt][fn][r] + bv);
      }
    }
  }
}

// fused windowed attention: one block per (window-pair, head). 9 waves.
// Q in registers (A-frag direct from global); Ps wave-private; ONE barrier total.
__global__ __launch_bounds__(576) void attn_win(
    const unsigned short* __restrict__ qkv,
    const unsigned short* __restrict__ bw,
    unsigned short* __restrict__ outp)
{
  __shared__ unsigned short Ks[144][40];
  __shared__ unsigned short Vst[32][160];
  __shared__ unsigned short Ps[144][160];   // rows wv*16.. are wave-private

  int b = blockIdx.x;
  int head = b % 6;
  int wt = b / 6;
  int tw = wt & 63;
  int t = threadIdx.x;
  int lane = t & 63;
  int wv = t >> 6;
  int lg = lane >> 4, lr = lane & 15;

  // stage K (row-major) and V (transposed) to LDS
  {
    int tok = t >> 2, c0 = (t & 3)*8;
    size_t base = ((size_t)wt*144 + tok)*576 + head*32 + c0;
    u16x8 kv = *(const u16x8*)(qkv + base + 192);
    u16x8 vv = *(const u16x8*)(qkv + base + 384);
    *(u16x8*)&Ks[tok][c0] = kv;
    #pragma unroll
    for (int i=0;i<8;i++) Vst[c0+i][tok] = vv[i];
  }
  if (t < 512) Vst[t >> 4][144 + (t & 15)] = 0;

  // Q fragment straight to registers: lane holds row (wv*16+lr), k = lg*8..+7
  bf16x8 qf = *(const bf16x8*)(qkv + ((size_t)wt*144 + wv*16 + lr)*576 + head*32 + lg*8);

  // bias fragments (coalesced)
  u16x8 bv0, bv1, bv2, bv3, bv4;
  {
    size_t sbase = ((((size_t)(tw*6 + head))*9 + wv)*5*64 + lane)*8;
    bv0 = *(const u16x8*)(bw + sbase);
    bv1 = *(const u16x8*)(bw + sbase + 64*8);
    bv2 = *(const u16x8*)(bw + sbase + 2*64*8);
    bv3 = *(const u16x8*)(bw + sbase + 3*64*8);
    bv4 = *(const u16x8*)(bw + sbase + 4*64*8);
  }
  __syncthreads();   // K/V staged; the ONLY block-wide barrier

  // S = (Q K^T)*scale + bias   (scale folded post-MFMA; exact)
  float s[9][4];
  #pragma unroll
  for (int ct=0; ct<9; ct++){
    bf16x8 bb = *(const bf16x8*)&Ks[ct*16 + lr][lg*8];
    f32x4 d = {0.f,0.f,0.f,0.f};
    d = __builtin_amdgcn_mfma_f32_16x16x32_bf16(qf, bb, d, 0,0,0);
    #pragma unroll
    for (int r=0;r<4;r++){
      const int e = ct*4 + r;
      unsigned short bu =
        (e < 8)  ? bv0[e & 7] :
        (e < 16) ? bv1[e & 7] :
        (e < 24) ? bv2[e & 7] :
        (e < 32) ? bv3[e & 7] : bv4[e & 7];
      s[ct][r] = fmaf(d[r], 0.17677669529663687f, b2f(bu));
    }
  }

  float mx[4] = {-1e30f,-1e30f,-1e30f,-1e30f};
  #pragma unroll
  for (int ct=0; ct<9; ct++)
    #pragma unroll
    for (int r=0;r<4;r++) mx[r] = fmaxf(mx[r], s[ct][r]);
  #pragma unroll
  for (int off=1; off<16; off<<=1)
    #pragma unroll
    for (int r=0;r<4;r++) mx[r] = fmaxf(mx[r], __shfl_xor(mx[r], off));
  float sm[4] = {0.f,0.f,0.f,0.f};
  #pragma unroll
  for (int ct=0; ct<9; ct++)
    #pragma unroll
    for (int r=0;r<4;r++){ s[ct][r] = __expf(s[ct][r] - mx[r]); sm[r] += s[ct][r]; }
  #pragma unroll
  for (int off=1; off<16; off<<=1)
    #pragma unroll
    for (int r=0;r<4;r++) sm[r] += __shfl_xor(sm[r], off);
  float inv[4];
  #pragma unroll
  for (int r=0;r<4;r++) inv[r] = 1.0f / sm[r];

  // write P (wave-private rows; intra-wave lgkmcnt ordering, no barrier)
  #pragma unroll
  for (int ct=0; ct<9; ct++)
    #pragma unroll
    for (int r=0;r<4;r++)
      Ps[wv*16 + lg*4 + r][ct*16 + lr] = f2b(s[ct][r] * inv[r]);
  #pragma unroll
  for (int r=0;r<4;r++) Ps[wv*16 + lg*4 + r][144 + lr] = 0;

  #pragma unroll
  for (int ct2=0; ct2<2; ct2++){
    f32x4 o = {0.f,0.f,0.f,0.f};
    #pragma unroll
    for (int kt=0; kt<5; kt++){
      bf16x8 a  = *(const bf16x8*)&Ps[wv*16 + lr][kt*32 + lg*8];
      bf16x8 bb = *(const bf16x8*)&Vst[ct2*16 + lr][kt*32 + lg*8];
      o = __builtin_amdgcn_mfma_f32_16x16x32_bf16(a, bb, o, 0,0,0);
    }
    size_t rb = ((size_t)wt*144 + wv*16 + lg*4)*192 + head*32 + ct2*16 + lr;
    #pragma unroll
    for (int r=0;r<4;r++) outp[rb + (size_t)r*192] = f2b(o[r]);
  }
}

// un-window (+unroll +crop) + LN + residual
__global__ __launch_bounds__(256) void unwin_ln(
  const unsigned short* __restrict__ ywin,
  const float* __restrict__ xsrc,
  const float* __restrict__ g, const float* __restrict__ bb,
  float* __restrict__ outf, unsigned short* __restrict__ outb, int roll)
{
  int tok = blockIdx.x*4 + (threadIdx.x>>6);
  if (tok >= NTOK) return;
  int lane = threadIdx.x & 63;
  int z = tok / (91*180);
  int rem = tok % (91*180);
  int h = rem / 180, wc = rem % 180;
  int zz=z, hh=h, ww=wc;
  if (roll){ zz = (z+7)&7; hh = (h+93)%96; ww = (wc+174)%180; }
  int nz = zz>>1, wz = zz&1;
  int nh = hh/6,  wh = hh%6;
  int nw = ww/12, w2 = ww%12;
  size_t row = ((size_t)(nw*64 + nz*16 + nh))*144 + wz*72 + wh*12 + w2;
  const unsigned short* yr = ywin + row*192;
  float v[3]; float s=0.f, ss=0.f;
  #pragma unroll
  for (int i=0;i<3;i++){ v[i] = b2f(yr[lane + i*64]); s += v[i]; ss += v[i]*v[i]; }
  #pragma unroll
  for (int off=32; off>=1; off>>=1){ s += __shfl_xor(s, off); ss += __shfl_xor(ss, off); }
  float mean = s * (1.0f/192.0f);
  float var = ss * (1.0f/192.0f) - mean*mean;
  float rinv = rsqrtf(var + 1e-5f);
  size_t tb = (size_t)tok*192;
  #pragma unroll
  for (int i=0;i<3;i++){
    int d = lane + i*64;
    float o = xsrc[tb + d] + ((v[i]-mean)*rinv*g[d] + bb[d]);
    outf[tb+d] = o;
    outb[tb+d] = f2b(o);
  }
}

// fused MLP + final LN + residual: out = xmid + LN( gelu(A@W1+b1) @ W2 + b2 )
// 256 rows/block, 8 waves x 32 rows; double-buffered weight chunks, 1 barrier/iter.
__global__ __launch_bounds__(512) void mlp_fused_ln(
    const unsigned short* __restrict__ A,    // [M][192] bf16
    const unsigned short* __restrict__ W1t,  // [768][192]
    const float* __restrict__ bias1,         // [768]
    const unsigned short* __restrict__ W2t,  // [192][768]
    const float* __restrict__ mbias2,        // [192]
    const float* __restrict__ xmid,          // [M][192] f32
    const float* __restrict__ lng,           // [192]
    const float* __restrict__ lnb,           // [192]
    float* __restrict__ outF,                // [M][192] f32
    int M)
{
  __shared__ unsigned short W1s[2][32][196];
  __shared__ unsigned short W2s[2][192][44];
  __shared__ unsigned short Hs[8][32][40];
  __shared__ float b1s[768];
  __shared__ float eps[576];                // [mb2 | lng | lnb]
  int m0 = blockIdx.x*256;
  int t = threadIdx.x, lane = t & 63, w = t >> 6;
  int lg = lane >> 4, lr = lane & 15;

  bf16x8 afrA[6], afrB[6];
  {
    int ra = m0 + w*32 + lr, rb = ra + 16;
    if (ra < M){
      const unsigned short* ap = A + (size_t)ra*192 + lg*8;
      #pragma unroll
      for (int ks=0; ks<6; ks++) afrA[ks] = *(const bf16x8*)(ap + ks*32);
    } else {
      #pragma unroll
      for (int ks=0; ks<6; ks++)
        #pragma unroll
        for (int j=0;j<8;j++) afrA[ks][j] = 0;
    }
    if (rb < M){
      const unsigned short* ap = A + (size_t)rb*192 + lg*8;
      #pragma unroll
      for (int ks=0; ks<6; ks++) afrB[ks] = *(const bf16x8*)(ap + ks*32);
    } else {
      #pragma unroll
      for (int ks=0; ks<6; ks++)
        #pragma unroll
        for (int j=0;j<8;j++) afrB[ks][j] = 0;
    }
  }

  b1s[t] = bias1[t];
  if (t < 256) b1s[512 + t] = bias1[512 + t];
  if (t < 192){ eps[t] = mbias2[t]; eps[192 + t] = lng[t]; eps[384 + t] = lnb[t]; }

  int i1r[2], i1c[2], i2r[2], i2c[2];
  #pragma unroll
  for (int i=0;i<2;i++){
    int idx = t + i*512;
    i1r[i] = idx/24; i1c[i] = (idx%24)*8;
    i2r[i] = idx/4;  i2c[i] = (idx&3)*8;
  }
  bool g2nd = (t + 512) < 768;

  {
    u16x8 a0 = *(const u16x8*)(W1t + (size_t)i1r[0]*192 + i1c[0]);
    u16x8 b0 = *(const u16x8*)(W2t + (size_t)i2r[0]*768 + i2c[0]);
    *(u16x8*)&W1s[0][i1r[0]][i1c[0]] = a0;
    *(u16x8*)&W2s[0][i2r[0]][i2c[0]] = b0;
    if (g2nd){
      u16x8 a1 = *(const u16x8*)(W1t + (size_t)i1r[1]*192 + i1c[1]);
      u16x8 b1v = *(const u16x8*)(W2t + (size_t)i2r[1]*768 + i2c[1]);
      *(u16x8*)&W1s[0][i1r[1]][i1c[1]] = a1;
      *(u16x8*)&W2s[0][i2r[1]][i2c[1]] = b1v;
    }
  }
  lds_barrier();

  f32x4 accA[12], accB[12];
  #pragma unroll
  for (int i=0;i<12;i++){ accA[i] = (f32x4){0.f,0.f,0.f,0.f}; accB[i] = (f32x4){0.f,0.f,0.f,0.f}; }

  u16x8 w1r[2], w2r[2];

  for (int it=0; it<24; ++it){
    int cur = it & 1;
    if (it < 23){
      int hc2 = (it+1)*32;
      w1r[0] = *(const u16x8*)(W1t + (size_t)(hc2 + i1r[0])*192 + i1c[0]);
      w2r[0] = *(const u16x8*)(W2t + (size_t)i2r[0]*768 + hc2 + i2c[0]);
      if (g2nd){
        w1r[1] = *(const u16x8*)(W1t + (size_t)(hc2 + i1r[1])*192 + i1c[1]);
        w2r[1] = *(const u16x8*)(W2t + (size_t)i2r[1]*768 + hc2 + i2c[1]);
      }
    }

    int hc = it*32;
    f32x4 h0a = (f32x4){0.f,0.f,0.f,0.f}, h1a = h0a, h0b = h0a, h1b = h0a;
    #pragma unroll
    for (int ks=0; ks<6; ks++){
      bf16x8 b0  = *(const bf16x8*)&W1s[cur][2*lr    ][ks*32 + lg*8];
      bf16x8 b1f = *(const bf16x8*)&W1s[cur][2*lr + 1][ks*32 + lg*8];
      h0a = __builtin_amdgcn_mfma_f32_16x16x32_bf16(afrA[ks], b0,  h0a, 0,0,0);
      h1a = __builtin_amdgcn_mfma_f32_16x16x32_bf16(afrA[ks], b1f, h1a, 0,0,0);
      h0b = __builtin_amdgcn_mfma_f32_16x16x32_bf16(afrB[ks], b0,  h0b, 0,0,0);
      h1b = __builtin_amdgcn_mfma_f32_16x16x32_bf16(afrB[ks], b1f, h1b, 0,0,0);
    }
    float bb0 = b1s[hc + 2*lr];
    float bb1 = b1s[hc + 2*lr + 1];
    #pragma unroll
    for (int r=0;r<4;r++){
      *(unsigned*)&Hs[w][lg*4 + r][2*lr] =
          pk_bf16(gelu_fast(h0a[r] + bb0), gelu_fast(h1a[r] + bb1));
      *(unsigned*)&Hs[w][16 + lg*4 + r][2*lr] =
          pk_bf16(gelu_fast(h0b[r] + bb0), gelu_fast(h1b[r] + bb1));
    }
    bf16x8 paA = *(const bf16x8*)&Hs[w][lr][lg*8];
    bf16x8 paB = *(const bf16x8*)&Hs[w][16 + lr][lg*8];
    #pragma unroll
    for (int f=0; f<6; f++){
      bf16x8 c0 = *(const bf16x8*)&W2s[cur][f*32 + 2*lr    ][lg*8];
      bf16x8 c1 = *(const bf16x8*)&W2s[cur][f*32 + 2*lr + 1][lg*8];
      accA[2*f]   = __builtin_amdgcn_mfma_f32_16x16x32_bf16(paA, c0, accA[2*f],   0,0,0);
      accA[2*f+1] = __builtin_amdgcn_mfma_f32_16x16x32_bf16(paA, c1, accA[2*f+1], 0,0,0);
      accB[2*f]   = __builtin_amdgcn_mfma_f32_16x16x32_bf16(paB, c0, accB[2*f],   0,0,0);
      accB[2*f+1] = __builtin_amdgcn_mfma_f32_16x16x32_bf16(paB, c1, accB[2*f+1], 0,0,0);
    }

    if (it < 23){
      int nxt = cur ^ 1;
      *(u16x8*)&W1s[nxt][i1r[0]][i1c[0]] = w1r[0];
      *(u16x8*)&W2s[nxt][i2r[0]][i2c[0]] = w2r[0];
      if (g2nd){
        *(u16x8*)&W1s[nxt][i1r[1]][i1c[1]] = w1r[1];
        *(u16x8*)&W2s[nxt][i2r[1]][i2c[1]] = w2r[1];
      }
    }
    lds_barrier();
  }

  #pragma unroll
  for (int gsel=0; gsel<2; gsel++){
    f32x4* acc = gsel ? accB : accA;
    #pragma unroll
    for (int r=0;r<4;r++){
      int row = m0 + w*32 + gsel*16 + lg*4 + r;
      float s = 0.f, ss = 0.f;
      #pragma unroll
      for (int f=0; f<6; f++){
        float v0 = acc[2*f][r]   + eps[f*32 + 2*lr];
        float v1 = acc[2*f+1][r] + eps[f*32 + 2*lr + 1];
        s += v0 + v1; ss += v0*v0 + v1*v1;
      }
      #pragma unroll
      for (int off=1; off<16; off<<=1){ s += __shfl_xor(s, off); ss += __shfl_xor(ss, off); }
      float mean = s * (1.0f/192.0f);
      float var  = ss * (1.0f/192.0f) - mean*mean;
      float rinv = rsqrtf(var + 1e-5f);
      if (row < M){
        size_t base = (size_t)row*192;
        #pragma unroll
        for (int f=0; f<6; f++){
          int c0 = f*32 + 2*lr;
          float v0 = acc[2*f][r]   + eps[c0];
          float v1 = acc[2*f+1][r] + eps[c0 + 1];
          f32x2 xm = *(const f32x2*)&xmid[base + c0];
          f32x2 o;
          o[0] = xm[0] + (v0 - mean)*rinv*eps[192 + c0]     + eps[384 + c0];
          o[1] = xm[1] + (v1 - mean)*rinv*eps[192 + c0 + 1] + eps[384 + c0 + 1];
          *(f32x2*)&outF[base + c0] = o;
        }
      }
    }
  }
}

extern "C" void kernel_launch(void* const* d_in, const int* in_sizes, int n_in,
                              void* d_out, int out_size, void* d_ws, size_t ws_size,
                              hipStream_t stream)
{
  const float* x_in    = (const float*)d_in[0];
  const float* qkvw    = (const float*)d_in[1];
  const float* qkvbias = (const float*)d_in[2];
  const float* projw   = (const float*)d_in[3];
  const float* projbias= (const float*)d_in[4];
  const float* btab    = (const float*)d_in[5];
  const float* n1g = (const float*)d_in[6];
  const float* n1b = (const float*)d_in[7];
  const float* n2g = (const float*)d_in[8];
  const float* n2b = (const float*)d_in[9];
  const float* w1  = (const float*)d_in[10];
  const float* b1  = (const float*)d_in[11];
  const float* w2  = (const float*)d_in[12];
  const float* b2  = (const float*)d_in[13];
  float* outp = (float*)d_out;

  const size_t REG_A = (size_t)NTOKW*192;
  const size_t REG_B = (size_t)NTOKW*576;
  const size_t W_QT  = (size_t)2*576*192;
  const size_t W_PT  = (size_t)2*192*192;
  const size_t W_1T  = (size_t)2*768*192;
  const size_t W_2T  = (size_t)2*192*768;
  const size_t TOT_SH = REG_A + REG_B + W_QT + W_PT + W_1T + W_2T;
  const size_t NEEDED = TOT_SH*2 + (size_t)NTOK*192*4;
  if (ws_size < NEEDED) return;

  unsigned short* ws16 = (unsigned short*)d_ws;
  size_t off = 0;
  unsigned short* regA = ws16 + off; off += REG_A;   // xw / attn-out / xmidb
  unsigned short* regB = ws16 + off; off += REG_B;   // qkv-out / ywin
  unsigned short* wqt  = ws16 + off; off += W_QT;
  unsigned short* wpt  = ws16 + off; off += W_PT;
  unsigned short* w1t  = ws16 + off; off += W_1T;
  unsigned short* w2t  = ws16 + off; off += W_2T;
  float* xmidf = (float*)(ws16 + off);
  unsigned short* bw = (unsigned short*)xmidf;   // alias: dead before unwin_ln writes xmidf

  for (int dep=0; dep<2; dep++){
    transp<<<(192*576+255)/256,256,0,stream>>>(qkvw + (size_t)dep*192*576,
                                               wqt + (size_t)dep*576*192, 192, 576);
    transp<<<(192*192+255)/256,256,0,stream>>>(projw + (size_t)dep*192*192,
                                               wpt + (size_t)dep*192*192, 192, 192);
    transp<<<(192*768+255)/256,256,0,stream>>>(w1 + (size_t)dep*192*768,
                                               w1t + (size_t)dep*768*192, 192, 768);
    transp<<<(768*192+255)/256,256,0,stream>>>(w2 + (size_t)dep*768*192,
                                               w2t + (size_t)dep*192*768, 768, 192);
  }

  for (int dep=0; dep<2; dep++){
    int roll = dep;
    const float* xs = (dep==0) ? x_in : outp;
    float* xout = outp;

    gather_win<<<NTOKW*24/256, 256, 0, stream>>>(xs, regA, roll);

    dim3 g1(NTOKW/128, 3);     // N=576
    gemm_k192<<<g1, 512, 0, stream>>>(regA, wqt + (size_t)dep*576*192,
                                      qkvbias + dep*576, regB, 576);

    bias_pre<<<(384*9*5*64)/256, 256, 0, stream>>>(btab + (size_t)dep*3312*384, bw, roll);

    attn_win<<<960*6, 576, 0, stream>>>(regB, bw, regA);

    dim3 g2(NTOKW/128, 1);     // N=192
    gemm_k192<<<g2, 512, 0, stream>>>(regA, wpt + (size_t)dep*192*192,
                                      projbias + dep*192, regB, 192);

    unwin_ln<<<NTOK/4, 256, 0, stream>>>(regB, xs, n1g + dep*192, n1b + dep*192,
                                         xmidf, regA, roll);

    mlp_fused_ln<<<(NTOK+255)/256, 512, 0, stream>>>(
        regA, w1t + (size_t)dep*768*192, b1 + dep*768,
        w2t + (size_t)dep*192*768, b2 + dep*192,
        xmidf, n2g + dep*192, n2b + dep*192, xout, NTOK);
  }
}

// Round 17
// 974.792 us; speedup vs baseline: 1.4332x; 1.0165x over previous
//
#include <hip/hip_runtime.h>
#include <math.h>

#define NTOK   131040   // 8*91*180
#define NTOKW  138240   // 15*64*144

typedef __attribute__((ext_vector_type(8))) short bf16x8;
typedef __attribute__((ext_vector_type(8))) unsigned short u16x8;
typedef __attribute__((ext_vector_type(4))) float f32x4;
typedef __attribute__((ext_vector_type(2))) float f32x2;

__device__ __forceinline__ float b2f(unsigned short u){
  union { unsigned u; float f; } v; v.u = ((unsigned)u) << 16; return v.f;
}
__device__ __forceinline__ unsigned short f2b(float f){
  union { float f; unsigned u; } v; v.f = f;
  unsigned r = v.u + 0x7FFFu + ((v.u >> 16) & 1u);
  return (unsigned short)(r >> 16);
}
// tanh-GELU via rcpf (no f32 div sequence); |err vs erf-GELU| ~3e-4
__device__ __forceinline__ float gelu_fast(float x){
  float t = 0.79788456080286536f * (x + 0.044715f * x * x * x);
  float e = __expf(2.0f * t);
  float th = 1.0f - 2.0f * __builtin_amdgcn_rcpf(e + 1.0f);
  return 0.5f * x * (1.0f + th);
}
__device__ __forceinline__ unsigned pk_bf16(float lo, float hi){
  unsigned r;
  asm("v_cvt_pk_bf16_f32 %0, %1, %2" : "=v"(r) : "v"(lo), "v"(hi));
  return r;
}
__device__ __forceinline__ void lds_barrier(){
  asm volatile("s_waitcnt lgkmcnt(0)" ::: "memory");
  __builtin_amdgcn_sched_barrier(0);
  __builtin_amdgcn_s_barrier();
  __builtin_amdgcn_sched_barrier(0);
}

// transpose-cast ALL weights (both depths) in one launch.
// segments (K,N): qkv (192,576) x2, proj (192,192) x2, w1 (192,768) x2, w2 (768,192) x2
__global__ __launch_bounds__(256) void transp_all(
    const float* __restrict__ qkvw, const float* __restrict__ projw,
    const float* __restrict__ w1,   const float* __restrict__ w2,
    unsigned short* __restrict__ wqt, unsigned short* __restrict__ wpt,
    unsigned short* __restrict__ w1t, unsigned short* __restrict__ w2t)
{
  int i = blockIdx.x*256 + threadIdx.x;   // < 885888
  // segment sizes: 110592*2, 36864*2, 147456*2, 147456*2
  const float* src; unsigned short* dst; int K, N, off;
  if (i < 221184){ int d = i / 110592; off = i % 110592;
    src = qkvw + (size_t)d*110592; dst = wqt + (size_t)d*110592; K = 192; N = 576; }
  else if (i < 294912){ int j = i - 221184; int d = j / 36864; off = j % 36864;
    src = projw + (size_t)d*36864; dst = wpt + (size_t)d*36864; K = 192; N = 192; }
  else if (i < 589824){ int j = i - 294912; int d = j / 147456; off = j % 147456;
    src = w1 + (size_t)d*147456; dst = w1t + (size_t)d*147456; K = 192; N = 768; }
  else { int j = i - 589824; int d = j / 147456; off = j % 147456;
    src = w2 + (size_t)d*147456; dst = w2t + (size_t)d*147456; K = 768; N = 192; }
  int n = off / K, k = off % K;
  dst[off] = f2b(src[(size_t)k*N + n]);
}

// precompute bias+mask in MFMA-fragment layout; ONE u16x8 store per thread.
__global__ __launch_bounds__(256) void bias_pre(
    const float* __restrict__ btab,
    unsigned short* __restrict__ bw,
    int roll)
{
  int gid = blockIdx.x*256 + threadIdx.x;   // < 384*9*5*64
  int lane = gid & 63;
  int rem  = gid >> 6;
  int vec  = rem % 5;
  int rem2 = rem / 5;
  int wv   = rem2 % 9;
  int slice= rem2 / 9;
  int tw = slice / 6;
  int nz = tw >> 4, nh = tw & 15;
  u16x8 out;
  #pragma unroll
  for (int elem=0; elem<8; elem++){
    int e = vec*8 + elem;
    unsigned short o = 0;
    if (e < 36){
      int ct = e >> 2, r = e & 3;
      int i = wv*16 + (lane>>4)*4 + r;
      int j = ct*16 + (lane & 15);
      int ia = i/72, ib = (i%72)/12, ic = i%12;
      int ja = j/72, jb = (j%72)/12, jc = j%12;
      int idx = (ia + 2*ja)*828 + (ib + 6*jb)*23 + (ic - jc + 11);
      float v = btab[(size_t)idx*384 + slice];
      if (roll){
        int zi = nz*2+ia, hi = nh*6+ib, zj = nz*2+ja, hj = nh*6+jb;
        int ri = 3*((zi<6)?0:((zi<7)?1:2)) + ((hi<90)?0:((hi<93)?1:2));
        int rj = 3*((zj<6)?0:((zj<7)?1:2)) + ((hj<90)?0:((hj<93)?1:2));
        if (ri != rj) v -= 100.0f;
      }
      o = f2b(v);
    }
    out[elem] = o;
  }
  *(u16x8*)(bw + (size_t)gid*8) = out;
}

// window-partition gather (+pad +roll), fp32 -> bf16
__global__ __launch_bounds__(256) void gather_win(const float* __restrict__ x,
                                                  unsigned short* __restrict__ xw,
                                                  int roll){
  int gid = blockIdx.x*256 + threadIdx.x;
  int row = gid / 24;
  int dp  = gid % 24;
  int tok = row % 144;
  int wt  = row / 144;
  int tw  = wt & 63;
  int w   = wt >> 6;
  int nz = tw >> 4, nh = tw & 15;
  int wz = tok / 72; int rem = tok % 72; int wh = rem / 12; int ww = rem % 12;
  int z = nz*2 + wz, h = nh*6 + wh, wc = w*12 + ww;
  if (roll){ z = (z+1)&7; h = (h+3)%96; wc = (wc+6)%180; }
  int d0 = dp*8;
  u16x8 o;
  if (h < 91){
    const float* s = x + ((size_t)((z*91 + h)*180 + wc))*192 + d0;
    #pragma unroll
    for (int i=0;i<8;i++) o[i] = f2b(s[i]);
  } else {
    #pragma unroll
    for (int i=0;i<8;i++) o[i] = 0;
  }
  *(u16x8*)(xw + (size_t)row*192 + d0) = o;
}

// K=192 GEMM: C[M x N] = A[M x 192] @ Bt[N x 192]^T + bias
__global__ __launch_bounds__(512) void gemm_k192(
    const unsigned short* __restrict__ A,
    const unsigned short* __restrict__ Bt,
    const float* __restrict__ bias,
    unsigned short* __restrict__ C,
    int N)
{
  __shared__ unsigned short Bst[192][200];
  int m0 = blockIdx.x * 128;
  int n0 = blockIdx.y * 192;
  int t = threadIdx.x;
  int lane = t & 63, w = t >> 6;
  int wm = w >> 2, wn = w & 3;
  int lg = lane >> 4, lr = lane & 15;

  #pragma unroll
  for (int i=0;i<9;i++){
    int idx = t + i*512;
    int r = idx / 24, c = (idx % 24)*8;
    *(u16x8*)&Bst[r][c] = *(const u16x8*)(Bt + (size_t)(n0 + r)*192 + c);
  }
  __syncthreads();

  const unsigned short* aRow = A + (size_t)(m0 + wm*64 + lr)*192 + lg*8;

  f32x4 acc[4][3];
  #pragma unroll
  for (int a=0;a<4;a++)
    #pragma unroll
    for (int b=0;b<3;b++) acc[a][b] = (f32x4){0.f,0.f,0.f,0.f};

  bf16x8 aP[2][6];
  #pragma unroll
  for (int ks=0; ks<6; ks++) aP[0][ks] = *(const bf16x8*)(aRow + ks*32);

  #pragma unroll
  for (int rt=0; rt<4; rt++){
    if (rt < 3){
      const unsigned short* an = aRow + (size_t)(rt+1)*16*192;
      #pragma unroll
      for (int ks=0; ks<6; ks++) aP[(rt+1)&1][ks] = *(const bf16x8*)(an + ks*32);
    }
    #pragma unroll
    for (int ks=0; ks<6; ks++){
      bf16x8 b0 = *(const bf16x8*)&Bst[wn*48 +      lr][ks*32 + lg*8];
      bf16x8 b1 = *(const bf16x8*)&Bst[wn*48 + 16 + lr][ks*32 + lg*8];
      bf16x8 b2 = *(const bf16x8*)&Bst[wn*48 + 32 + lr][ks*32 + lg*8];
      bf16x8 af = aP[rt&1][ks];
      acc[rt][0] = __builtin_amdgcn_mfma_f32_16x16x32_bf16(af, b0, acc[rt][0], 0,0,0);
      acc[rt][1] = __builtin_amdgcn_mfma_f32_16x16x32_bf16(af, b1, acc[rt][1], 0,0,0);
      acc[rt][2] = __builtin_amdgcn_mfma_f32_16x16x32_bf16(af, b2, acc[rt][2], 0,0,0);
    }
  }

  #pragma unroll
  for (int rt=0; rt<4; rt++){
    #pragma unroll
    for (int fn=0; fn<3; fn++){
      int colg = n0 + wn*48 + fn*16 + lr;
      float bv = bias[colg];
      #pragma unroll
      for (int r=0;r<4;r++){
        int rowg = m0 + wm*64 + rt*16 + lg*4 + r;
        C[(size_t)rowg*N + colg] = f2b(acc[rt][fn][r] + bv);
      }
    }
  }
}

// fused windowed attention: one block per (window-pair, head). 9 waves.
// Q in registers; Ps wave-private; ONE barrier; packed coalesced output.
__global__ __launch_bounds__(576) void attn_win(
    const unsigned short* __restrict__ qkv,
    const unsigned short* __restrict__ bw,
    unsigned short* __restrict__ outp)
{
  __shared__ unsigned short Ks[144][40];
  __shared__ unsigned short Vst[32][160];
  __shared__ unsigned short Ps[144][160];   // rows wv*16.. are wave-private

  int b = blockIdx.x;
  int head = b % 6;
  int wt = b / 6;
  int tw = wt & 63;
  int t = threadIdx.x;
  int lane = t & 63;
  int wv = t >> 6;
  int lg = lane >> 4, lr = lane & 15;

  {
    int tok = t >> 2, c0 = (t & 3)*8;
    size_t base = ((size_t)wt*144 + tok)*576 + head*32 + c0;
    u16x8 kv = *(const u16x8*)(qkv + base + 192);
    u16x8 vv = *(const u16x8*)(qkv + base + 384);
    *(u16x8*)&Ks[tok][c0] = kv;
    #pragma unroll
    for (int i=0;i<8;i++) Vst[c0+i][tok] = vv[i];
  }
  if (t < 512) Vst[t >> 4][144 + (t & 15)] = 0;

  bf16x8 qf = *(const bf16x8*)(qkv + ((size_t)wt*144 + wv*16 + lr)*576 + head*32 + lg*8);

  u16x8 bv0, bv1, bv2, bv3, bv4;
  {
    size_t sbase = ((((size_t)(tw*6 + head))*9 + wv)*5*64 + lane)*8;
    bv0 = *(const u16x8*)(bw + sbase);
    bv1 = *(const u16x8*)(bw + sbase + 64*8);
    bv2 = *(const u16x8*)(bw + sbase + 2*64*8);
    bv3 = *(const u16x8*)(bw + sbase + 3*64*8);
    bv4 = *(const u16x8*)(bw + sbase + 4*64*8);
  }
  __syncthreads();   // K/V staged; the only block-wide barrier

  float s[9][4];
  #pragma unroll
  for (int ct=0; ct<9; ct++){
    bf16x8 bb = *(const bf16x8*)&Ks[ct*16 + lr][lg*8];
    f32x4 d = {0.f,0.f,0.f,0.f};
    d = __builtin_amdgcn_mfma_f32_16x16x32_bf16(qf, bb, d, 0,0,0);
    #pragma unroll
    for (int r=0;r<4;r++){
      const int e = ct*4 + r;
      unsigned short bu =
        (e < 8)  ? bv0[e & 7] :
        (e < 16) ? bv1[e & 7] :
        (e < 24) ? bv2[e & 7] :
        (e < 32) ? bv3[e & 7] : bv4[e & 7];
      s[ct][r] = fmaf(d[r], 0.17677669529663687f, b2f(bu));
    }
  }

  float mx[4] = {-1e30f,-1e30f,-1e30f,-1e30f};
  #pragma unroll
  for (int ct=0; ct<9; ct++)
    #pragma unroll
    for (int r=0;r<4;r++) mx[r] = fmaxf(mx[r], s[ct][r]);
  #pragma unroll
  for (int off=1; off<16; off<<=1)
    #pragma unroll
    for (int r=0;r<4;r++) mx[r] = fmaxf(mx[r], __shfl_xor(mx[r], off));
  float sm[4] = {0.f,0.f,0.f,0.f};
  #pragma unroll
  for (int ct=0; ct<9; ct++)
    #pragma unroll
    for (int r=0;r<4;r++){ s[ct][r] = __expf(s[ct][r] - mx[r]); sm[r] += s[ct][r]; }
  #pragma unroll
  for (int off=1; off<16; off<<=1)
    #pragma unroll
    for (int r=0;r<4;r++) sm[r] += __shfl_xor(sm[r], off);
  float inv[4];
  #pragma unroll
  for (int r=0;r<4;r++) inv[r] = 1.0f / sm[r];

  // write P (wave-private rows; intra-wave DS ordering, no barrier)
  #pragma unroll
  for (int ct=0; ct<9; ct++)
    #pragma unroll
    for (int r=0;r<4;r++)
      Ps[wv*16 + lg*4 + r][ct*16 + lr] = f2b(s[ct][r] * inv[r]);
  #pragma unroll
  for (int r=0;r<4;r++) Ps[wv*16 + lg*4 + r][144 + lr] = 0;

  // O = P V  (keep both col-tiles in regs)
  f32x4 o0 = (f32x4){0.f,0.f,0.f,0.f}, o1 = o0;
  #pragma unroll
  for (int kt=0; kt<5; kt++){
    bf16x8 a  = *(const bf16x8*)&Ps[wv*16 + lr][kt*32 + lg*8];
    bf16x8 v0 = *(const bf16x8*)&Vst[     lr][kt*32 + lg*8];
    bf16x8 v1 = *(const bf16x8*)&Vst[16 + lr][kt*32 + lg*8];
    o0 = __builtin_amdgcn_mfma_f32_16x16x32_bf16(a, v0, o0, 0,0,0);
    o1 = __builtin_amdgcn_mfma_f32_16x16x32_bf16(a, v1, o1, 0,0,0);
  }

  // packed output: transpose O through the wave's (now-dead) Ps strip,
  // then one coalesced u16x8 store per lane.
  #pragma unroll
  for (int r=0;r<4;r++){
    Ps[wv*16 + lg*4 + r][lr]      = f2b(o0[r]);
    Ps[wv*16 + lg*4 + r][16 + lr] = f2b(o1[r]);
  }
  {
    int row = lane >> 2, c0 = (lane & 3)*8;
    u16x8 ov = *(const u16x8*)&Ps[wv*16 + row][c0];
    *(u16x8*)(outp + ((size_t)wt*144 + wv*16 + row)*192 + head*32 + c0) = ov;
  }
}

// un-window (+unroll +crop) + LN + residual
__global__ __launch_bounds__(256) void unwin_ln(
  const unsigned short* __restrict__ ywin,
  const float* __restrict__ xsrc,
  const float* __restrict__ g, const float* __restrict__ bb,
  float* __restrict__ outf, unsigned short* __restrict__ outb, int roll)
{
  int tok = blockIdx.x*4 + (threadIdx.x>>6);
  if (tok >= NTOK) return;
  int lane = threadIdx.x & 63;
  int z = tok / (91*180);
  int rem = tok % (91*180);
  int h = rem / 180, wc = rem % 180;
  int zz=z, hh=h, ww=wc;
  if (roll){ zz = (z+7)&7; hh = (h+93)%96; ww = (wc+174)%180; }
  int nz = zz>>1, wz = zz&1;
  int nh = hh/6,  wh = hh%6;
  int nw = ww/12, w2 = ww%12;
  size_t row = ((size_t)(nw*64 + nz*16 + nh))*144 + wz*72 + wh*12 + w2;
  const unsigned short* yr = ywin + row*192;
  float v[3]; float s=0.f, ss=0.f;
  #pragma unroll
  for (int i=0;i<3;i++){ v[i] = b2f(yr[lane + i*64]); s += v[i]; ss += v[i]*v[i]; }
  #pragma unroll
  for (int off=32; off>=1; off>>=1){ s += __shfl_xor(s, off); ss += __shfl_xor(ss, off); }
  float mean = s * (1.0f/192.0f);
  float var = ss * (1.0f/192.0f) - mean*mean;
  float rinv = rsqrtf(var + 1e-5f);
  size_t tb = (size_t)tok*192;
  #pragma unroll
  for (int i=0;i<3;i++){
    int d = lane + i*64;
    float o = xsrc[tb + d] + ((v[i]-mean)*rinv*g[d] + bb[d]);
    outf[tb+d] = o;
    outb[tb+d] = f2b(o);
  }
}

// fused MLP + final LN + residual (frozen best config):
// 256 rows/block, 8 waves x 32 rows; double-buffered weight chunks, 1 barrier/iter.
__global__ __launch_bounds__(512) void mlp_fused_ln(
    const unsigned short* __restrict__ A,
    const unsigned short* __restrict__ W1t,
    const float* __restrict__ bias1,
    const unsigned short* __restrict__ W2t,
    const float* __restrict__ mbias2,
    const float* __restrict__ xmid,
    const float* __restrict__ lng,
    const float* __restrict__ lnb,
    float* __restrict__ outF,
    int M)
{
  __shared__ unsigned short W1s[2][32][196];
  __shared__ unsigned short W2s[2][192][44];
  __shared__ unsigned short Hs[8][32][40];
  __shared__ float b1s[768];
  __shared__ float eps[576];
  int m0 = blockIdx.x*256;
  int t = threadIdx.x, lane = t & 63, w = t >> 6;
  int lg = lane >> 4, lr = lane & 15;

  bf16x8 afrA[6], afrB[6];
  {
    int ra = m0 + w*32 + lr, rb = ra + 16;
    if (ra < M){
      const unsigned short* ap = A + (size_t)ra*192 + lg*8;
      #pragma unroll
      for (int ks=0; ks<6; ks++) afrA[ks] = *(const bf16x8*)(ap + ks*32);
    } else {
      #pragma unroll
      for (int ks=0; ks<6; ks++)
        #pragma unroll
        for (int j=0;j<8;j++) afrA[ks][j] = 0;
    }
    if (rb < M){
      const unsigned short* ap = A + (size_t)rb*192 + lg*8;
      #pragma unroll
      for (int ks=0; ks<6; ks++) afrB[ks] = *(const bf16x8*)(ap + ks*32);
    } else {
      #pragma unroll
      for (int ks=0; ks<6; ks++)
        #pragma unroll
        for (int j=0;j<8;j++) afrB[ks][j] = 0;
    }
  }

  b1s[t] = bias1[t];
  if (t < 256) b1s[512 + t] = bias1[512 + t];
  if (t < 192){ eps[t] = mbias2[t]; eps[192 + t] = lng[t]; eps[384 + t] = lnb[t]; }

  int i1r[2], i1c[2], i2r[2], i2c[2];
  #pragma unroll
  for (int i=0;i<2;i++){
    int idx = t + i*512;
    i1r[i] = idx/24; i1c[i] = (idx%24)*8;
    i2r[i] = idx/4;  i2c[i] = (idx&3)*8;
  }
  bool g2nd = (t + 512) < 768;

  {
    u16x8 a0 = *(const u16x8*)(W1t + (size_t)i1r[0]*192 + i1c[0]);
    u16x8 b0 = *(const u16x8*)(W2t + (size_t)i2r[0]*768 + i2c[0]);
    *(u16x8*)&W1s[0][i1r[0]][i1c[0]] = a0;
    *(u16x8*)&W2s[0][i2r[0]][i2c[0]] = b0;
    if (g2nd){
      u16x8 a1 = *(const u16x8*)(W1t + (size_t)i1r[1]*192 + i1c[1]);
      u16x8 b1v = *(const u16x8*)(W2t + (size_t)i2r[1]*768 + i2c[1]);
      *(u16x8*)&W1s[0][i1r[1]][i1c[1]] = a1;
      *(u16x8*)&W2s[0][i2r[1]][i2c[1]] = b1v;
    }
  }
  lds_barrier();

  f32x4 accA[12], accB[12];
  #pragma unroll
  for (int i=0;i<12;i++){ accA[i] = (f32x4){0.f,0.f,0.f,0.f}; accB[i] = (f32x4){0.f,0.f,0.f,0.f}; }

  u16x8 w1r[2], w2r[2];

  for (int it=0; it<24; ++it){
    int cur = it & 1;
    if (it < 23){
      int hc2 = (it+1)*32;
      w1r[0] = *(const u16x8*)(W1t + (size_t)(hc2 + i1r[0])*192 + i1c[0]);
      w2r[0] = *(const u16x8*)(W2t + (size_t)i2r[0]*768 + hc2 + i2c[0]);
      if (g2nd){
        w1r[1] = *(const u16x8*)(W1t + (size_t)(hc2 + i1r[1])*192 + i1c[1]);
        w2r[1] = *(const u16x8*)(W2t + (size_t)i2r[1]*768 + hc2 + i2c[1]);
      }
    }

    int hc = it*32;
    f32x4 h0a = (f32x4){0.f,0.f,0.f,0.f}, h1a = h0a, h0b = h0a, h1b = h0a;
    #pragma unroll
    for (int ks=0; ks<6; ks++){
      bf16x8 b0  = *(const bf16x8*)&W1s[cur][2*lr    ][ks*32 + lg*8];
      bf16x8 b1f = *(const bf16x8*)&W1s[cur][2*lr + 1][ks*32 + lg*8];
      h0a = __builtin_amdgcn_mfma_f32_16x16x32_bf16(afrA[ks], b0,  h0a, 0,0,0);
      h1a = __builtin_amdgcn_mfma_f32_16x16x32_bf16(afrA[ks], b1f, h1a, 0,0,0);
      h0b = __builtin_amdgcn_mfma_f32_16x16x32_bf16(afrB[ks], b0,  h0b, 0,0,0);
      h1b = __builtin_amdgcn_mfma_f32_16x16x32_bf16(afrB[ks], b1f, h1b, 0,0,0);
    }
    float bb0 = b1s[hc + 2*lr];
    float bb1 = b1s[hc + 2*lr + 1];
    #pragma unroll
    for (int r=0;r<4;r++){
      *(unsigned*)&Hs[w][lg*4 + r][2*lr] =
          pk_bf16(gelu_fast(h0a[r] + bb0), gelu_fast(h1a[r] + bb1));
      *(unsigned*)&Hs[w][16 + lg*4 + r][2*lr] =
          pk_bf16(gelu_fast(h0b[r] + bb0), gelu_fast(h1b[r] + bb1));
    }
    bf16x8 paA = *(const bf16x8*)&Hs[w][lr][lg*8];
    bf16x8 paB = *(const bf16x8*)&Hs[w][16 + lr][lg*8];
    #pragma unroll
    for (int f=0; f<6; f++){
      bf16x8 c0 = *(const bf16x8*)&W2s[cur][f*32 + 2*lr    ][lg*8];
      bf16x8 c1 = *(const bf16x8*)&W2s[cur][f*32 + 2*lr + 1][lg*8];
      accA[2*f]   = __builtin_amdgcn_mfma_f32_16x16x32_bf16(paA, c0, accA[2*f],   0,0,0);
      accA[2*f+1] = __builtin_amdgcn_mfma_f32_16x16x32_bf16(paA, c1, accA[2*f+1], 0,0,0);
      accB[2*f]   = __builtin_amdgcn_mfma_f32_16x16x32_bf16(paB, c0, accB[2*f],   0,0,0);
      accB[2*f+1] = __builtin_amdgcn_mfma_f32_16x16x32_bf16(paB, c1, accB[2*f+1], 0,0,0);
    }

    if (it < 23){
      int nxt = cur ^ 1;
      *(u16x8*)&W1s[nxt][i1r[0]][i1c[0]] = w1r[0];
      *(u16x8*)&W2s[nxt][i2r[0]][i2c[0]] = w2r[0];
      if (g2nd){
        *(u16x8*)&W1s[nxt][i1r[1]][i1c[1]] = w1r[1];
        *(u16x8*)&W2s[nxt][i2r[1]][i2c[1]] = w2r[1];
      }
    }
    lds_barrier();
  }

  #pragma unroll
  for (int gsel=0; gsel<2; gsel++){
    f32x4* acc = gsel ? accB : accA;
    #pragma unroll
    for (int r=0;r<4;r++){
      int row = m0 + w*32 + gsel*16 + lg*4 + r;
      float s = 0.f, ss = 0.f;
      #pragma unroll
      for (int f=0; f<6; f++){
        float v0 = acc[2*f][r]   + eps[f*32 + 2*lr];
        float v1 = acc[2*f+1][r] + eps[f*32 + 2*lr + 1];
        s += v0 + v1; ss += v0*v0 + v1*v1;
      }
      #pragma unroll
      for (int off=1; off<16; off<<=1){ s += __shfl_xor(s, off); ss += __shfl_xor(ss, off); }
      float mean = s * (1.0f/192.0f);
      float var  = ss * (1.0f/192.0f) - mean*mean;
      float rinv = rsqrtf(var + 1e-5f);
      if (row < M){
        size_t base = (size_t)row*192;
        #pragma unroll
        for (int f=0; f<6; f++){
          int c0 = f*32 + 2*lr;
          float v0 = acc[2*f][r]   + eps[c0];
          float v1 = acc[2*f+1][r] + eps[c0 + 1];
          f32x2 xm = *(const f32x2*)&xmid[base + c0];
          f32x2 o;
          o[0] = xm[0] + (v0 - mean)*rinv*eps[192 + c0]     + eps[384 + c0];
          o[1] = xm[1] + (v1 - mean)*rinv*eps[192 + c0 + 1] + eps[384 + c0 + 1];
          *(f32x2*)&outF[base + c0] = o;
        }
      }
    }
  }
}

extern "C" void kernel_launch(void* const* d_in, const int* in_sizes, int n_in,
                              void* d_out, int out_size, void* d_ws, size_t ws_size,
                              hipStream_t stream)
{
  const float* x_in    = (const float*)d_in[0];
  const float* qkvw    = (const float*)d_in[1];
  const float* qkvbias = (const float*)d_in[2];
  const float* projw   = (const float*)d_in[3];
  const float* projbias= (const float*)d_in[4];
  const float* btab    = (const float*)d_in[5];
  const float* n1g = (const float*)d_in[6];
  const float* n1b = (const float*)d_in[7];
  const float* n2g = (const float*)d_in[8];
  const float* n2b = (const float*)d_in[9];
  const float* w1  = (const float*)d_in[10];
  const float* b1  = (const float*)d_in[11];
  const float* w2  = (const float*)d_in[12];
  const float* b2  = (const float*)d_in[13];
  float* outp = (float*)d_out;

  const size_t REG_A = (size_t)NTOKW*192;
  const size_t REG_B = (size_t)NTOKW*576;
  const size_t W_QT  = (size_t)2*576*192;
  const size_t W_PT  = (size_t)2*192*192;
  const size_t W_1T  = (size_t)2*768*192;
  const size_t W_2T  = (size_t)2*192*768;
  const size_t TOT_SH = REG_A + REG_B + W_QT + W_PT + W_1T + W_2T;
  const size_t NEEDED = TOT_SH*2 + (size_t)NTOK*192*4;
  if (ws_size < NEEDED) return;

  unsigned short* ws16 = (unsigned short*)d_ws;
  size_t off = 0;
  unsigned short* regA = ws16 + off; off += REG_A;   // xw / attn-out / xmidb
  unsigned short* regB = ws16 + off; off += REG_B;   // qkv-out / ywin
  unsigned short* wqt  = ws16 + off; off += W_QT;
  unsigned short* wpt  = ws16 + off; off += W_PT;
  unsigned short* w1t  = ws16 + off; off += W_1T;
  unsigned short* w2t  = ws16 + off; off += W_2T;
  float* xmidf = (float*)(ws16 + off);
  unsigned short* bw = (unsigned short*)xmidf;   // alias: dead before unwin_ln writes xmidf

  transp_all<<<(885888+255)/256, 256, 0, stream>>>(qkvw, projw, w1, w2,
                                                   wqt, wpt, w1t, w2t);

  for (int dep=0; dep<2; dep++){
    int roll = dep;
    const float* xs = (dep==0) ? x_in : outp;
    float* xout = outp;

    gather_win<<<NTOKW*24/256, 256, 0, stream>>>(xs, regA, roll);

    dim3 g1(NTOKW/128, 3);     // N=576
    gemm_k192<<<g1, 512, 0, stream>>>(regA, wqt + (size_t)dep*576*192,
                                      qkvbias + dep*576, regB, 576);

    bias_pre<<<(384*9*5*64)/256, 256, 0, stream>>>(btab + (size_t)dep*3312*384, bw, roll);

    attn_win<<<960*6, 576, 0, stream>>>(regB, bw, regA);

    dim3 g2(NTOKW/128, 1);     // N=192
    gemm_k192<<<g2, 512, 0, stream>>>(regA, wpt + (size_t)dep*192*192,
                                      projbias + dep*192, regB, 192);

    unwin_ln<<<NTOK/4, 256, 0, stream>>>(regB, xs, n1g + dep*192, n1b + dep*192,
                                         xmidf, regA, roll);

    mlp_fused_ln<<<(NTOK+255)/256, 512, 0, stream>>>(
        regA, w1t + (size_t)dep*768*192, b1 + dep*768,
        w2t + (size_t)dep*192*768, b2 + dep*192,
        xmidf, n2g + dep*192, n2b + dep*192, xout, NTOK);
  }
}

// Round 18
// 959.311 us; speedup vs baseline: 1.4564x; 1.0161x over previous
//
#include <hip/hip_runtime.h>
#include <math.h>

#define NTOK   131040   // 8*91*180
#define NTOKW  138240   // 15*64*144

typedef __attribute__((ext_vector_type(8))) short bf16x8;
typedef __attribute__((ext_vector_type(8))) unsigned short u16x8;
typedef __attribute__((ext_vector_type(4))) float f32x4;
typedef __attribute__((ext_vector_type(2))) float f32x2;

__device__ __forceinline__ float b2f(unsigned short u){
  union { unsigned u; float f; } v; v.u = ((unsigned)u) << 16; return v.f;
}
__device__ __forceinline__ unsigned short f2b(float f){
  union { float f; unsigned u; } v; v.f = f;
  unsigned r = v.u + 0x7FFFu + ((v.u >> 16) & 1u);
  return (unsigned short)(r >> 16);
}
// tanh-GELU via rcpf (no f32 div sequence); |err vs erf-GELU| ~3e-4
__device__ __forceinline__ float gelu_fast(float x){
  float t = 0.79788456080286536f * (x + 0.044715f * x * x * x);
  float e = __expf(2.0f * t);
  float th = 1.0f - 2.0f * __builtin_amdgcn_rcpf(e + 1.0f);
  return 0.5f * x * (1.0f + th);
}
__device__ __forceinline__ unsigned pk_bf16(float lo, float hi){
  unsigned r;
  asm("v_cvt_pk_bf16_f32 %0, %1, %2" : "=v"(r) : "v"(lo), "v"(hi));
  return r;
}
__device__ __forceinline__ void lds_barrier(){
  asm volatile("s_waitcnt lgkmcnt(0)" ::: "memory");
  __builtin_amdgcn_sched_barrier(0);
  __builtin_amdgcn_s_barrier();
  __builtin_amdgcn_sched_barrier(0);
}

// transpose-cast ALL weights (both depths) in one launch.
__global__ __launch_bounds__(256) void transp_all(
    const float* __restrict__ qkvw, const float* __restrict__ projw,
    const float* __restrict__ w1,   const float* __restrict__ w2,
    unsigned short* __restrict__ wqt, unsigned short* __restrict__ wpt,
    unsigned short* __restrict__ w1t, unsigned short* __restrict__ w2t)
{
  int i = blockIdx.x*256 + threadIdx.x;   // < 885888
  const float* src; unsigned short* dst; int K, N, off;
  if (i < 221184){ int d = i / 110592; off = i % 110592;
    src = qkvw + (size_t)d*110592; dst = wqt + (size_t)d*110592; K = 192; N = 576; }
  else if (i < 294912){ int j = i - 221184; int d = j / 36864; off = j % 36864;
    src = projw + (size_t)d*36864; dst = wpt + (size_t)d*36864; K = 192; N = 192; }
  else if (i < 589824){ int j = i - 294912; int d = j / 147456; off = j % 147456;
    src = w1 + (size_t)d*147456; dst = w1t + (size_t)d*147456; K = 192; N = 768; }
  else { int j = i - 589824; int d = j / 147456; off = j % 147456;
    src = w2 + (size_t)d*147456; dst = w2t + (size_t)d*147456; K = 768; N = 192; }
  int n = off / K, k = off % K;
  dst[off] = f2b(src[(size_t)k*N + n]);
}

// precompute bias+mask in MFMA-fragment layout; ONE u16x8 store per thread.
__global__ __launch_bounds__(256) void bias_pre(
    const float* __restrict__ btab,
    unsigned short* __restrict__ bw,
    int roll)
{
  int gid = blockIdx.x*256 + threadIdx.x;   // < 384*9*5*64
  int lane = gid & 63;
  int rem  = gid >> 6;
  int vec  = rem % 5;
  int rem2 = rem / 5;
  int wv   = rem2 % 9;
  int slice= rem2 / 9;
  int tw = slice / 6;
  int nz = tw >> 4, nh = tw & 15;
  u16x8 out;
  #pragma unroll
  for (int elem=0; elem<8; elem++){
    int e = vec*8 + elem;
    unsigned short o = 0;
    if (e < 36){
      int ct = e >> 2, r = e & 3;
      int i = wv*16 + (lane>>4)*4 + r;
      int j = ct*16 + (lane & 15);
      int ia = i/72, ib = (i%72)/12, ic = i%12;
      int ja = j/72, jb = (j%72)/12, jc = j%12;
      int idx = (ia + 2*ja)*828 + (ib + 6*jb)*23 + (ic - jc + 11);
      float v = btab[(size_t)idx*384 + slice];
      if (roll){
        int zi = nz*2+ia, hi = nh*6+ib, zj = nz*2+ja, hj = nh*6+jb;
        int ri = 3*((zi<6)?0:((zi<7)?1:2)) + ((hi<90)?0:((hi<93)?1:2));
        int rj = 3*((zj<6)?0:((zj<7)?1:2)) + ((hj<90)?0:((hj<93)?1:2));
        if (ri != rj) v -= 100.0f;
      }
      o = f2b(v);
    }
    out[elem] = o;
  }
  *(u16x8*)(bw + (size_t)gid*8) = out;
}

// window-partition gather (+pad +roll), fp32 -> bf16
__global__ __launch_bounds__(256) void gather_win(const float* __restrict__ x,
                                                  unsigned short* __restrict__ xw,
                                                  int roll){
  int gid = blockIdx.x*256 + threadIdx.x;
  int row = gid / 24;
  int dp  = gid % 24;
  int tok = row % 144;
  int wt  = row / 144;
  int tw  = wt & 63;
  int w   = wt >> 6;
  int nz = tw >> 4, nh = tw & 15;
  int wz = tok / 72; int rem = tok % 72; int wh = rem / 12; int ww = rem % 12;
  int z = nz*2 + wz, h = nh*6 + wh, wc = w*12 + ww;
  if (roll){ z = (z+1)&7; h = (h+3)%96; wc = (wc+6)%180; }
  int d0 = dp*8;
  u16x8 o;
  if (h < 91){
    const float* s = x + ((size_t)((z*91 + h)*180 + wc))*192 + d0;
    #pragma unroll
    for (int i=0;i<8;i++) o[i] = f2b(s[i]);
  } else {
    #pragma unroll
    for (int i=0;i<8;i++) o[i] = 0;
  }
  *(u16x8*)(xw + (size_t)row*192 + d0) = o;
}

// K=192 GEMM: C[M x N] = A[M x 192] @ Bt[N x 192]^T + bias.
// qkv (N=576): 1-D grid 3240, siblings (same m-tile, 3 n-tiles) placed 8 apart
//   -> same XCD -> A-panel L2-reuse. proj (N=192): plain 1-D grid.
// C staged through LDS (union over dead B) -> coalesced u16x8 stores.
__global__ __launch_bounds__(512) void gemm_k192(
    const unsigned short* __restrict__ A,
    const unsigned short* __restrict__ Bt,
    const float* __restrict__ bias,
    unsigned short* __restrict__ C,
    int N)
{
  __shared__ union {
    unsigned short B[192][200];
    unsigned short Cs[128][200];
  } U;
  int m0, n0;
  if (N == 576){
    int lin = blockIdx.x;          // < 3240 = 135 groups * 24
    int grp = lin / 24;
    int rem = lin % 24;
    m0 = (grp*8 + (rem & 7)) * 128;
    n0 = (rem >> 3) * 192;
  } else {
    m0 = blockIdx.x * 128;
    n0 = 0;
  }
  int t = threadIdx.x;
  int lane = t & 63, w = t >> 6;
  int wm = w >> 2, wn = w & 3;
  int lg = lane >> 4, lr = lane & 15;

  #pragma unroll
  for (int i=0;i<9;i++){
    int idx = t + i*512;
    int r = idx / 24, c = (idx % 24)*8;
    *(u16x8*)&U.B[r][c] = *(const u16x8*)(Bt + (size_t)(n0 + r)*192 + c);
  }
  __syncthreads();

  const unsigned short* aRow = A + (size_t)(m0 + wm*64 + lr)*192 + lg*8;

  f32x4 acc[4][3];
  #pragma unroll
  for (int a=0;a<4;a++)
    #pragma unroll
    for (int b=0;b<3;b++) acc[a][b] = (f32x4){0.f,0.f,0.f,0.f};

  bf16x8 aP[2][6];
  #pragma unroll
  for (int ks=0; ks<6; ks++) aP[0][ks] = *(const bf16x8*)(aRow + ks*32);

  #pragma unroll
  for (int rt=0; rt<4; rt++){
    if (rt < 3){
      const unsigned short* an = aRow + (size_t)(rt+1)*16*192;
      #pragma unroll
      for (int ks=0; ks<6; ks++) aP[(rt+1)&1][ks] = *(const bf16x8*)(an + ks*32);
    }
    #pragma unroll
    for (int ks=0; ks<6; ks++){
      bf16x8 b0 = *(const bf16x8*)&U.B[wn*48 +      lr][ks*32 + lg*8];
      bf16x8 b1 = *(const bf16x8*)&U.B[wn*48 + 16 + lr][ks*32 + lg*8];
      bf16x8 b2 = *(const bf16x8*)&U.B[wn*48 + 32 + lr][ks*32 + lg*8];
      bf16x8 af = aP[rt&1][ks];
      acc[rt][0] = __builtin_amdgcn_mfma_f32_16x16x32_bf16(af, b0, acc[rt][0], 0,0,0);
      acc[rt][1] = __builtin_amdgcn_mfma_f32_16x16x32_bf16(af, b1, acc[rt][1], 0,0,0);
      acc[rt][2] = __builtin_amdgcn_mfma_f32_16x16x32_bf16(af, b2, acc[rt][2], 0,0,0);
    }
  }

  // epilogue: bias + pack through LDS (B region is dead) -> coalesced stores
  float bv[3];
  #pragma unroll
  for (int fn=0; fn<3; fn++) bv[fn] = bias[n0 + wn*48 + fn*16 + lr];

  lds_barrier();   // all B reads complete before overlay
  #pragma unroll
  for (int rt=0; rt<4; rt++)
    #pragma unroll
    for (int fn=0; fn<3; fn++)
      #pragma unroll
      for (int r=0;r<4;r++)
        U.Cs[wm*64 + rt*16 + lg*4 + r][wn*48 + fn*16 + lr] = f2b(acc[rt][fn][r] + bv[fn]);
  lds_barrier();

  #pragma unroll
  for (int i=0;i<6;i++){
    int idx = t + i*512;        // < 3072
    int r = idx / 24, c = (idx % 24)*8;
    u16x8 v = *(const u16x8*)&U.Cs[r][c];
    *(u16x8*)(C + (size_t)(m0 + r)*N + n0 + c) = v;
  }
}

// fused windowed attention: one block per (window-pair, head). 9 waves.
// Q in registers; Ps wave-private; ONE barrier; packed coalesced output.
__global__ __launch_bounds__(576) void attn_win(
    const unsigned short* __restrict__ qkv,
    const unsigned short* __restrict__ bw,
    unsigned short* __restrict__ outp)
{
  __shared__ unsigned short Ks[144][40];
  __shared__ unsigned short Vst[32][160];
  __shared__ unsigned short Ps[144][160];   // rows wv*16.. are wave-private

  int b = blockIdx.x;
  int head = b % 6;
  int wt = b / 6;
  int tw = wt & 63;
  int t = threadIdx.x;
  int lane = t & 63;
  int wv = t >> 6;
  int lg = lane >> 4, lr = lane & 15;

  {
    int tok = t >> 2, c0 = (t & 3)*8;
    size_t base = ((size_t)wt*144 + tok)*576 + head*32 + c0;
    u16x8 kv = *(const u16x8*)(qkv + base + 192);
    u16x8 vv = *(const u16x8*)(qkv + base + 384);
    *(u16x8*)&Ks[tok][c0] = kv;
    #pragma unroll
    for (int i=0;i<8;i++) Vst[c0+i][tok] = vv[i];
  }
  if (t < 512) Vst[t >> 4][144 + (t & 15)] = 0;

  bf16x8 qf = *(const bf16x8*)(qkv + ((size_t)wt*144 + wv*16 + lr)*576 + head*32 + lg*8);

  u16x8 bv0, bv1, bv2, bv3, bv4;
  {
    size_t sbase = ((((size_t)(tw*6 + head))*9 + wv)*5*64 + lane)*8;
    bv0 = *(const u16x8*)(bw + sbase);
    bv1 = *(const u16x8*)(bw + sbase + 64*8);
    bv2 = *(const u16x8*)(bw + sbase + 2*64*8);
    bv3 = *(const u16x8*)(bw + sbase + 3*64*8);
    bv4 = *(const u16x8*)(bw + sbase + 4*64*8);
  }
  __syncthreads();   // K/V staged; the only block-wide barrier

  float s[9][4];
  #pragma unroll
  for (int ct=0; ct<9; ct++){
    bf16x8 bb = *(const bf16x8*)&Ks[ct*16 + lr][lg*8];
    f32x4 d = {0.f,0.f,0.f,0.f};
    d = __builtin_amdgcn_mfma_f32_16x16x32_bf16(qf, bb, d, 0,0,0);
    #pragma unroll
    for (int r=0;r<4;r++){
      const int e = ct*4 + r;
      unsigned short bu =
        (e < 8)  ? bv0[e & 7] :
        (e < 16) ? bv1[e & 7] :
        (e < 24) ? bv2[e & 7] :
        (e < 32) ? bv3[e & 7] : bv4[e & 7];
      s[ct][r] = fmaf(d[r], 0.17677669529663687f, b2f(bu));
    }
  }

  float mx[4] = {-1e30f,-1e30f,-1e30f,-1e30f};
  #pragma unroll
  for (int ct=0; ct<9; ct++)
    #pragma unroll
    for (int r=0;r<4;r++) mx[r] = fmaxf(mx[r], s[ct][r]);
  #pragma unroll
  for (int off=1; off<16; off<<=1)
    #pragma unroll
    for (int r=0;r<4;r++) mx[r] = fmaxf(mx[r], __shfl_xor(mx[r], off));
  float sm[4] = {0.f,0.f,0.f,0.f};
  #pragma unroll
  for (int ct=0; ct<9; ct++)
    #pragma unroll
    for (int r=0;r<4;r++){ s[ct][r] = __expf(s[ct][r] - mx[r]); sm[r] += s[ct][r]; }
  #pragma unroll
  for (int off=1; off<16; off<<=1)
    #pragma unroll
    for (int r=0;r<4;r++) sm[r] += __shfl_xor(sm[r], off);
  float inv[4];
  #pragma unroll
  for (int r=0;r<4;r++) inv[r] = 1.0f / sm[r];

  #pragma unroll
  for (int ct=0; ct<9; ct++)
    #pragma unroll
    for (int r=0;r<4;r++)
      Ps[wv*16 + lg*4 + r][ct*16 + lr] = f2b(s[ct][r] * inv[r]);
  #pragma unroll
  for (int r=0;r<4;r++) Ps[wv*16 + lg*4 + r][144 + lr] = 0;

  f32x4 o0 = (f32x4){0.f,0.f,0.f,0.f}, o1 = o0;
  #pragma unroll
  for (int kt=0; kt<5; kt++){
    bf16x8 a  = *(const bf16x8*)&Ps[wv*16 + lr][kt*32 + lg*8];
    bf16x8 v0 = *(const bf16x8*)&Vst[     lr][kt*32 + lg*8];
    bf16x8 v1 = *(const bf16x8*)&Vst[16 + lr][kt*32 + lg*8];
    o0 = __builtin_amdgcn_mfma_f32_16x16x32_bf16(a, v0, o0, 0,0,0);
    o1 = __builtin_amdgcn_mfma_f32_16x16x32_bf16(a, v1, o1, 0,0,0);
  }

  #pragma unroll
  for (int r=0;r<4;r++){
    Ps[wv*16 + lg*4 + r][lr]      = f2b(o0[r]);
    Ps[wv*16 + lg*4 + r][16 + lr] = f2b(o1[r]);
  }
  {
    int row = lane >> 2, c0 = (lane & 3)*8;
    u16x8 ov = *(const u16x8*)&Ps[wv*16 + row][c0];
    *(u16x8*)(outp + ((size_t)wt*144 + wv*16 + row)*192 + head*32 + c0) = ov;
  }
}

// un-window (+unroll +crop) + LN + residual
__global__ __launch_bounds__(256) void unwin_ln(
  const unsigned short* __restrict__ ywin,
  const float* __restrict__ xsrc,
  const float* __restrict__ g, const float* __restrict__ bb,
  float* __restrict__ outf, unsigned short* __restrict__ outb, int roll)
{
  int tok = blockIdx.x*4 + (threadIdx.x>>6);
  if (tok >= NTOK) return;
  int lane = threadIdx.x & 63;
  int z = tok / (91*180);
  int rem = tok % (91*180);
  int h = rem / 180, wc = rem % 180;
  int zz=z, hh=h, ww=wc;
  if (roll){ zz = (z+7)&7; hh = (h+93)%96; ww = (wc+174)%180; }
  int nz = zz>>1, wz = zz&1;
  int nh = hh/6,  wh = hh%6;
  int nw = ww/12, w2 = ww%12;
  size_t row = ((size_t)(nw*64 + nz*16 + nh))*144 + wz*72 + wh*12 + w2;
  const unsigned short* yr = ywin + row*192;
  float v[3]; float s=0.f, ss=0.f;
  #pragma unroll
  for (int i=0;i<3;i++){ v[i] = b2f(yr[lane + i*64]); s += v[i]; ss += v[i]*v[i]; }
  #pragma unroll
  for (int off=32; off>=1; off>>=1){ s += __shfl_xor(s, off); ss += __shfl_xor(ss, off); }
  float mean = s * (1.0f/192.0f);
  float var = ss * (1.0f/192.0f) - mean*mean;
  float rinv = rsqrtf(var + 1e-5f);
  size_t tb = (size_t)tok*192;
  #pragma unroll
  for (int i=0;i<3;i++){
    int d = lane + i*64;
    float o = xsrc[tb + d] + ((v[i]-mean)*rinv*g[d] + bb[d]);
    outf[tb+d] = o;
    outb[tb+d] = f2b(o);
  }
}

// fused MLP + final LN + residual (frozen best config)
__global__ __launch_bounds__(512) void mlp_fused_ln(
    const unsigned short* __restrict__ A,
    const unsigned short* __restrict__ W1t,
    const float* __restrict__ bias1,
    const unsigned short* __restrict__ W2t,
    const float* __restrict__ mbias2,
    const float* __restrict__ xmid,
    const float* __restrict__ lng,
    const float* __restrict__ lnb,
    float* __restrict__ outF,
    int M)
{
  __shared__ unsigned short W1s[2][32][196];
  __shared__ unsigned short W2s[2][192][44];
  __shared__ unsigned short Hs[8][32][40];
  __shared__ float b1s[768];
  __shared__ float eps[576];
  int m0 = blockIdx.x*256;
  int t = threadIdx.x, lane = t & 63, w = t >> 6;
  int lg = lane >> 4, lr = lane & 15;

  bf16x8 afrA[6], afrB[6];
  {
    int ra = m0 + w*32 + lr, rb = ra + 16;
    if (ra < M){
      const unsigned short* ap = A + (size_t)ra*192 + lg*8;
      #pragma unroll
      for (int ks=0; ks<6; ks++) afrA[ks] = *(const bf16x8*)(ap + ks*32);
    } else {
      #pragma unroll
      for (int ks=0; ks<6; ks++)
        #pragma unroll
        for (int j=0;j<8;j++) afrA[ks][j] = 0;
    }
    if (rb < M){
      const unsigned short* ap = A + (size_t)rb*192 + lg*8;
      #pragma unroll
      for (int ks=0; ks<6; ks++) afrB[ks] = *(const bf16x8*)(ap + ks*32);
    } else {
      #pragma unroll
      for (int ks=0; ks<6; ks++)
        #pragma unroll
        for (int j=0;j<8;j++) afrB[ks][j] = 0;
    }
  }

  b1s[t] = bias1[t];
  if (t < 256) b1s[512 + t] = bias1[512 + t];
  if (t < 192){ eps[t] = mbias2[t]; eps[192 + t] = lng[t]; eps[384 + t] = lnb[t]; }

  int i1r[2], i1c[2], i2r[2], i2c[2];
  #pragma unroll
  for (int i=0;i<2;i++){
    int idx = t + i*512;
    i1r[i] = idx/24; i1c[i] = (idx%24)*8;
    i2r[i] = idx/4;  i2c[i] = (idx&3)*8;
  }
  bool g2nd = (t + 512) < 768;

  {
    u16x8 a0 = *(const u16x8*)(W1t + (size_t)i1r[0]*192 + i1c[0]);
    u16x8 b0 = *(const u16x8*)(W2t + (size_t)i2r[0]*768 + i2c[0]);
    *(u16x8*)&W1s[0][i1r[0]][i1c[0]] = a0;
    *(u16x8*)&W2s[0][i2r[0]][i2c[0]] = b0;
    if (g2nd){
      u16x8 a1 = *(const u16x8*)(W1t + (size_t)i1r[1]*192 + i1c[1]);
      u16x8 b1v = *(const u16x8*)(W2t + (size_t)i2r[1]*768 + i2c[1]);
      *(u16x8*)&W1s[0][i1r[1]][i1c[1]] = a1;
      *(u16x8*)&W2s[0][i2r[1]][i2c[1]] = b1v;
    }
  }
  lds_barrier();

  f32x4 accA[12], accB[12];
  #pragma unroll
  for (int i=0;i<12;i++){ accA[i] = (f32x4){0.f,0.f,0.f,0.f}; accB[i] = (f32x4){0.f,0.f,0.f,0.f}; }

  u16x8 w1r[2], w2r[2];

  for (int it=0; it<24; ++it){
    int cur = it & 1;
    if (it < 23){
      int hc2 = (it+1)*32;
      w1r[0] = *(const u16x8*)(W1t + (size_t)(hc2 + i1r[0])*192 + i1c[0]);
      w2r[0] = *(const u16x8*)(W2t + (size_t)i2r[0]*768 + hc2 + i2c[0]);
      if (g2nd){
        w1r[1] = *(const u16x8*)(W1t + (size_t)(hc2 + i1r[1])*192 + i1c[1]);
        w2r[1] = *(const u16x8*)(W2t + (size_t)i2r[1]*768 + hc2 + i2c[1]);
      }
    }

    int hc = it*32;
    f32x4 h0a = (f32x4){0.f,0.f,0.f,0.f}, h1a = h0a, h0b = h0a, h1b = h0a;
    #pragma unroll
    for (int ks=0; ks<6; ks++){
      bf16x8 b0  = *(const bf16x8*)&W1s[cur][2*lr    ][ks*32 + lg*8];
      bf16x8 b1f = *(const bf16x8*)&W1s[cur][2*lr + 1][ks*32 + lg*8];
      h0a = __builtin_amdgcn_mfma_f32_16x16x32_bf16(afrA[ks], b0,  h0a, 0,0,0);
      h1a = __builtin_amdgcn_mfma_f32_16x16x32_bf16(afrA[ks], b1f, h1a, 0,0,0);
      h0b = __builtin_amdgcn_mfma_f32_16x16x32_bf16(afrB[ks], b0,  h0b, 0,0,0);
      h1b = __builtin_amdgcn_mfma_f32_16x16x32_bf16(afrB[ks], b1f, h1b, 0,0,0);
    }
    float bb0 = b1s[hc + 2*lr];
    float bb1 = b1s[hc + 2*lr + 1];
    #pragma unroll
    for (int r=0;r<4;r++){
      *(unsigned*)&Hs[w][lg*4 + r][2*lr] =
          pk_bf16(gelu_fast(h0a[r] + bb0), gelu_fast(h1a[r] + bb1));
      *(unsigned*)&Hs[w][16 + lg*4 + r][2*lr] =
          pk_bf16(gelu_fast(h0b[r] + bb0), gelu_fast(h1b[r] + bb1));
    }
    bf16x8 paA = *(const bf16x8*)&Hs[w][lr][lg*8];
    bf16x8 paB = *(const bf16x8*)&Hs[w][16 + lr][lg*8];
    #pragma unroll
    for (int f=0; f<6; f++){
      bf16x8 c0 = *(const bf16x8*)&W2s[cur][f*32 + 2*lr    ][lg*8];
      bf16x8 c1 = *(const bf16x8*)&W2s[cur][f*32 + 2*lr + 1][lg*8];
      accA[2*f]   = __builtin_amdgcn_mfma_f32_16x16x32_bf16(paA, c0, accA[2*f],   0,0,0);
      accA[2*f+1] = __builtin_amdgcn_mfma_f32_16x16x32_bf16(paA, c1, accA[2*f+1], 0,0,0);
      accB[2*f]   = __builtin_amdgcn_mfma_f32_16x16x32_bf16(paB, c0, accB[2*f],   0,0,0);
      accB[2*f+1] = __builtin_amdgcn_mfma_f32_16x16x32_bf16(paB, c1, accB[2*f+1], 0,0,0);
    }

    if (it < 23){
      int nxt = cur ^ 1;
      *(u16x8*)&W1s[nxt][i1r[0]][i1c[0]] = w1r[0];
      *(u16x8*)&W2s[nxt][i2r[0]][i2c[0]] = w2r[0];
      if (g2nd){
        *(u16x8*)&W1s[nxt][i1r[1]][i1c[1]] = w1r[1];
        *(u16x8*)&W2s[nxt][i2r[1]][i2c[1]] = w2r[1];
      }
    }
    lds_barrier();
  }

  #pragma unroll
  for (int gsel=0; gsel<2; gsel++){
    f32x4* acc = gsel ? accB : accA;
    #pragma unroll
    for (int r=0;r<4;r++){
      int row = m0 + w*32 + gsel*16 + lg*4 + r;
      float s = 0.f, ss = 0.f;
      #pragma unroll
      for (int f=0; f<6; f++){
        float v0 = acc[2*f][r]   + eps[f*32 + 2*lr];
        float v1 = acc[2*f+1][r] + eps[f*32 + 2*lr + 1];
        s += v0 + v1; ss += v0*v0 + v1*v1;
      }
      #pragma unroll
      for (int off=1; off<16; off<<=1){ s += __shfl_xor(s, off); ss += __shfl_xor(ss, off); }
      float mean = s * (1.0f/192.0f);
      float var  = ss * (1.0f/192.0f) - mean*mean;
      float rinv = rsqrtf(var + 1e-5f);
      if (row < M){
        size_t base = (size_t)row*192;
        #pragma unroll
        for (int f=0; f<6; f++){
          int c0 = f*32 + 2*lr;
          float v0 = acc[2*f][r]   + eps[c0];
          float v1 = acc[2*f+1][r] + eps[c0 + 1];
          f32x2 xm = *(const f32x2*)&xmid[base + c0];
          f32x2 o;
          o[0] = xm[0] + (v0 - mean)*rinv*eps[192 + c0]     + eps[384 + c0];
          o[1] = xm[1] + (v1 - mean)*rinv*eps[192 + c0 + 1] + eps[384 + c0 + 1];
          *(f32x2*)&outF[base + c0] = o;
        }
      }
    }
  }
}

extern "C" void kernel_launch(void* const* d_in, const int* in_sizes, int n_in,
                              void* d_out, int out_size, void* d_ws, size_t ws_size,
                              hipStream_t stream)
{
  const float* x_in    = (const float*)d_in[0];
  const float* qkvw    = (const float*)d_in[1];
  const float* qkvbias = (const float*)d_in[2];
  const float* projw   = (const float*)d_in[3];
  const float* projbias= (const float*)d_in[4];
  const float* btab    = (const float*)d_in[5];
  const float* n1g = (const float*)d_in[6];
  const float* n1b = (const float*)d_in[7];
  const float* n2g = (const float*)d_in[8];
  const float* n2b = (const float*)d_in[9];
  const float* w1  = (const float*)d_in[10];
  const float* b1  = (const float*)d_in[11];
  const float* w2  = (const float*)d_in[12];
  const float* b2  = (const float*)d_in[13];
  float* outp = (float*)d_out;

  const size_t REG_A = (size_t)NTOKW*192;
  const size_t REG_B = (size_t)NTOKW*576;
  const size_t W_QT  = (size_t)2*576*192;
  const size_t W_PT  = (size_t)2*192*192;
  const size_t W_1T  = (size_t)2*768*192;
  const size_t W_2T  = (size_t)2*192*768;
  const size_t TOT_SH = REG_A + REG_B + W_QT + W_PT + W_1T + W_2T;
  const size_t NEEDED = TOT_SH*2 + (size_t)NTOK*192*4;
  if (ws_size < NEEDED) return;

  unsigned short* ws16 = (unsigned short*)d_ws;
  size_t off = 0;
  unsigned short* regA = ws16 + off; off += REG_A;   // xw / attn-out / xmidb
  unsigned short* regB = ws16 + off; off += REG_B;   // qkv-out / ywin
  unsigned short* wqt  = ws16 + off; off += W_QT;
  unsigned short* wpt  = ws16 + off; off += W_PT;
  unsigned short* w1t  = ws16 + off; off += W_1T;
  unsigned short* w2t  = ws16 + off; off += W_2T;
  float* xmidf = (float*)(ws16 + off);
  unsigned short* bw = (unsigned short*)xmidf;   // alias: dead before unwin_ln writes xmidf

  transp_all<<<(885888+255)/256, 256, 0, stream>>>(qkvw, projw, w1, w2,
                                                   wqt, wpt, w1t, w2t);

  for (int dep=0; dep<2; dep++){
    int roll = dep;
    const float* xs = (dep==0) ? x_in : outp;
    float* xout = outp;

    gather_win<<<NTOKW*24/256, 256, 0, stream>>>(xs, regA, roll);

    gemm_k192<<<3240, 512, 0, stream>>>(regA, wqt + (size_t)dep*576*192,
                                        qkvbias + dep*576, regB, 576);

    bias_pre<<<(384*9*5*64)/256, 256, 0, stream>>>(btab + (size_t)dep*3312*384, bw, roll);

    attn_win<<<960*6, 576, 0, stream>>>(regB, bw, regA);

    gemm_k192<<<1080, 512, 0, stream>>>(regA, wpt + (size_t)dep*192*192,
                                        projbias + dep*192, regB, 192);

    unwin_ln<<<NTOK/4, 256, 0, stream>>>(regB, xs, n1g + dep*192, n1b + dep*192,
                                         xmidf, regA, roll);

    mlp_fused_ln<<<(NTOK+255)/256, 512, 0, stream>>>(
        regA, w1t + (size_t)dep*768*192, b1 + dep*768,
        w2t + (size_t)dep*192*768, b2 + dep*192,
        xmidf, n2g + dep*192, n2b + dep*192, xout, NTOK);
  }
}